// Round 1
// baseline (1011.819 us; speedup 1.0000x reference)
//
#include <hip/hip_runtime.h>
#include <hip/hip_bf16.h>

#define NNODES 50000
#define NEDGES 800000
#define NGRAPHS 64
#define HID 128
#define NCLASSES 38
#define EPSBN 1e-5f

// ---------------- graph preprocessing ----------------

__global__ void init_kernel(float* deg, int* cnt, int* cursor, int N) {
    int i = blockIdx.x * blockDim.x + threadIdx.x;
    if (i < N) { deg[i] = 0.f; cnt[i] = 0; cursor[i] = 0; }
}

__global__ void deg_kernel(const int* __restrict__ ei, const float* __restrict__ ew,
                           float* deg, int E) {
    int e = blockIdx.x * blockDim.x + threadIdx.x;
    if (e < E) atomicAdd(&deg[ei[E + e]], ew[e]);
}

__global__ void dinv_kernel(float* deg_dinv, float* selfn, int N) {
    int i = blockIdx.x * blockDim.x + threadIdx.x;
    if (i < N) {
        float d = deg_dinv[i] + 1.0f;           // +1 for self-loop weight
        float di = rsqrtf(fmaxf(d, 1e-12f));
        deg_dinv[i] = di;
        selfn[i] = di * di;
    }
}

__global__ void count_kernel(const int* __restrict__ ei, int* cnt, int E) {
    int e = blockIdx.x * blockDim.x + threadIdx.x;
    if (e < E) atomicAdd(&cnt[ei[E + e]], 1);
}

__global__ __launch_bounds__(1024) void scan_kernel(const int* __restrict__ cnt,
                                                    int* __restrict__ row_start, int N) {
    __shared__ int part[1024];
    int t = threadIdx.x;
    int CH = (N + 1023) >> 10;
    int base = t * CH;
    int s = 0;
    for (int i = 0; i < CH; i++) { int idx = base + i; if (idx < N) s += cnt[idx]; }
    part[t] = s;
    __syncthreads();
    for (int o = 1; o < 1024; o <<= 1) {
        int v = (t >= o) ? part[t - o] : 0;
        __syncthreads();
        part[t] += v;
        __syncthreads();
    }
    int run = (t > 0) ? part[t - 1] : 0;
    for (int i = 0; i < CH; i++) {
        int idx = base + i;
        if (idx < N) { row_start[idx] = run; run += cnt[idx]; }
    }
    if (t == 0) row_start[N] = part[1023];
}

__global__ void fill_kernel(const int* __restrict__ ei, const float* __restrict__ ew,
                            const float* __restrict__ dinv, const int* __restrict__ row_start,
                            int* cursor, int* __restrict__ csr_src, float* __restrict__ csr_w,
                            int E) {
    int e = blockIdx.x * blockDim.x + threadIdx.x;
    if (e >= E) return;
    int s = ei[e], d = ei[E + e];
    int slot = row_start[d] + atomicAdd(&cursor[d], 1);
    csr_src[slot] = s;
    csr_w[slot] = dinv[s] * ew[e] * dinv[d];
}

// ---------------- fp32 GEMM: [M,128] @ [128,128] -> [M,128] ----------------

__global__ __launch_bounds__(256) void gemm_x128(const float* __restrict__ X,
                                                 const float* __restrict__ W,
                                                 float* __restrict__ H, int M) {
    __shared__ float Xs[16][132];
    __shared__ float Ws[16][132];
    const int tid = threadIdx.x;
    const int tr = tid >> 4;       // 0..15 (row group)
    const int tc = tid & 15;       // 0..15 (col group)
    const int row0 = blockIdx.x * 128;

    float acc[8][8];
#pragma unroll
    for (int i = 0; i < 8; i++)
#pragma unroll
        for (int j = 0; j < 8; j++) acc[i][j] = 0.f;

    for (int kt = 0; kt < 128; kt += 16) {
        // stage X tile [128 rows][16 k]
#pragma unroll
        for (int it = 0; it < 8; ++it) {
            int r = (tid >> 4) + 16 * it;
            int kk = tid & 15;
            int grow = row0 + r;
            Xs[kk][r] = (grow < M) ? X[grow * 128 + kt + kk] : 0.f;
        }
        // stage W tile [16 k][128 cols]
#pragma unroll
        for (int it = 0; it < 8; ++it) {
            int kk = (tid >> 7) + 2 * it;
            int c = tid & 127;
            Ws[kk][c] = W[(kt + kk) * 128 + c];
        }
        __syncthreads();
#pragma unroll
        for (int kk = 0; kk < 16; ++kk) {
            float xv[8], wv[8];
            *reinterpret_cast<float4*>(&xv[0]) = *reinterpret_cast<const float4*>(&Xs[kk][tr * 8]);
            *reinterpret_cast<float4*>(&xv[4]) = *reinterpret_cast<const float4*>(&Xs[kk][tr * 8 + 4]);
            *reinterpret_cast<float4*>(&wv[0]) = *reinterpret_cast<const float4*>(&Ws[kk][tc * 8]);
            *reinterpret_cast<float4*>(&wv[4]) = *reinterpret_cast<const float4*>(&Ws[kk][tc * 8 + 4]);
#pragma unroll
            for (int i = 0; i < 8; i++)
#pragma unroll
                for (int j = 0; j < 8; j++) acc[i][j] += xv[i] * wv[j];
        }
        __syncthreads();
    }
#pragma unroll
    for (int i = 0; i < 8; i++) {
        int grow = row0 + tr * 8 + i;
        if (grow < M) {
            float4 v0 = make_float4(acc[i][0], acc[i][1], acc[i][2], acc[i][3]);
            float4 v1 = make_float4(acc[i][4], acc[i][5], acc[i][6], acc[i][7]);
            *reinterpret_cast<float4*>(&H[grow * 128 + tc * 8]) = v0;
            *reinterpret_cast<float4*>(&H[grow * 128 + tc * 8 + 4]) = v1;
        }
    }
}

// ---------------- aggregation: OUT[d] = selfn[d]*H[d] + sum_e w*H[src] + b ----------------

__global__ __launch_bounds__(256) void agg_kernel(const float* __restrict__ H,
                                                  const int* __restrict__ row_start,
                                                  const int* __restrict__ csr_src,
                                                  const float* __restrict__ csr_w,
                                                  const float* __restrict__ selfn,
                                                  const float* __restrict__ bias,
                                                  float* __restrict__ OUT, int N) {
    int node = blockIdx.x * 2 + (threadIdx.x >> 7);
    int f = threadIdx.x & 127;
    if (node >= N) return;
    float acc = selfn[node] * H[node * 128 + f] + bias[f];
    int e0 = row_start[node], e1 = row_start[node + 1];
    for (int j = e0; j < e1; ++j) {
        acc += csr_w[j] * H[csr_src[j] * 128 + f];
    }
    OUT[node * 128 + f] = acc;
}

// ---------------- batchnorm stats + apply(+relu) ----------------

__global__ __launch_bounds__(256) void stats_kernel(const float* __restrict__ A,
                                                    float* __restrict__ gsum,
                                                    float* __restrict__ gss, int N) {
    int f = threadIdx.x & 127;
    int half = threadIdx.x >> 7;
    int rows_per_block = (N + gridDim.x - 1) / gridDim.x;
    int r0 = blockIdx.x * rows_per_block;
    int r1 = min(N, r0 + rows_per_block);
    float s = 0.f, ss = 0.f;
    for (int r = r0 + half; r < r1; r += 2) {
        float v = A[r * 128 + f];
        s += v; ss += v * v;
    }
    __shared__ float sh[256], sh2[256];
    sh[threadIdx.x] = s; sh2[threadIdx.x] = ss;
    __syncthreads();
    if (half == 0) {
        s += sh[threadIdx.x + 128];
        ss += sh2[threadIdx.x + 128];
        atomicAdd(&gsum[f], s);
        atomicAdd(&gss[f], ss);
    }
}

__global__ __launch_bounds__(256) void bnrelu_kernel(const float* __restrict__ A,
                                                     const float* __restrict__ gsum,
                                                     const float* __restrict__ gss,
                                                     const float* __restrict__ g,
                                                     const float* __restrict__ bt,
                                                     float* __restrict__ OUT, int N) {
    int i = blockIdx.x * blockDim.x + threadIdx.x;
    if (i >= N * 128) return;
    int f = i & 127;
    float invn = 1.0f / (float)N;
    float m = gsum[f] * invn;
    float var = gss[f] * invn - m * m;
    float xv = (A[i] - m) * rsqrtf(var + EPSBN) * g[f] + bt[f];
    OUT[i] = fmaxf(xv, 0.f);
}

// ---------------- pooling + head ----------------

__device__ __forceinline__ int lower_bound_dev(const int* arr, int n, int key) {
    int lo = 0, hi = n;
    while (lo < hi) {
        int mid = (lo + hi) >> 1;
        if (arr[mid] < key) lo = mid + 1; else hi = mid;
    }
    return lo;
}

__global__ __launch_bounds__(128) void pool_kernel(const float* __restrict__ H,
                                                   const int* __restrict__ batch,
                                                   float* __restrict__ pooled, int N) {
    int g = blockIdx.x >> 3, chunk = blockIdx.x & 7;
    int start = lower_bound_dev(batch, N, g);
    int end = lower_bound_dev(batch, N, g + 1);
    long long len = end - start;
    int c0 = start + (int)(len * chunk / 8);
    int c1 = start + (int)(len * (chunk + 1) / 8);
    int f = threadIdx.x;
    float acc = 0.f;
    for (int r = c0; r < c1; ++r) acc += H[r * 128 + f];
    atomicAdd(&pooled[g * 128 + f], acc);
}

__global__ __launch_bounds__(128) void head1_kernel(const float* __restrict__ pooled,
                                                    const float* __restrict__ Wn,
                                                    const float* __restrict__ bnb,
                                                    float* __restrict__ p2) {
    int g = blockIdx.x, f = threadIdx.x;
    __shared__ float row[128];
    row[f] = pooled[g * 128 + f];
    __syncthreads();
    float acc = bnb[f];
    for (int k = 0; k < 128; k++) acc += row[k] * Wn[k * 128 + f];
    p2[g * 128 + f] = acc;
}

__global__ __launch_bounds__(64) void head2_kernel(const float* __restrict__ p2,
                                                   const float* __restrict__ Wf,
                                                   const float* __restrict__ bf,
                                                   float* __restrict__ out) {
    int g = blockIdx.x, t = threadIdx.x;
    __shared__ float row[128];
    row[t] = p2[g * 128 + t];
    row[t + 64] = p2[g * 128 + 64 + t];
    __syncthreads();
    float acc = -1e30f;
    if (t < NCLASSES) {
        acc = bf[t];
        for (int k = 0; k < 128; k++) acc += row[k] * Wf[k * NCLASSES + t];
    }
    float m = acc;
    for (int o = 32; o > 0; o >>= 1) m = fmaxf(m, __shfl_xor(m, o));
    float e = (t < NCLASSES) ? expf(acc - m) : 0.f;
    float ssum = e;
    for (int o = 32; o > 0; o >>= 1) ssum += __shfl_xor(ssum, o);
    if (t < NCLASSES) out[g * NCLASSES + t] = acc - m - logf(ssum);
}

// ---------------- launch ----------------

extern "C" void kernel_launch(void* const* d_in, const int* in_sizes, int n_in,
                              void* d_out, int out_size, void* d_ws, size_t ws_size,
                              hipStream_t stream) {
    const float* x    = (const float*)d_in[0];
    const int*   ei   = (const int*)d_in[1];
    const float* ew   = (const float*)d_in[2];
    const int*   batch= (const int*)d_in[3];
    const float* W1   = (const float*)d_in[4];
    const float* b1   = (const float*)d_in[5];
    const float* g1   = (const float*)d_in[6];
    const float* bt1  = (const float*)d_in[7];
    const float* W2   = (const float*)d_in[8];
    const float* b2   = (const float*)d_in[9];
    const float* g2   = (const float*)d_in[10];
    const float* bt2  = (const float*)d_in[11];
    const float* W3   = (const float*)d_in[12];
    const float* b3   = (const float*)d_in[13];
    const float* Wn   = (const float*)d_in[14];
    const float* bnb  = (const float*)d_in[15];
    const float* Wf   = (const float*)d_in[16];
    const float* bf   = (const float*)d_in[17];
    float* out = (float*)d_out;
    (void)in_sizes; (void)n_in; (void)out_size; (void)ws_size;

    char* ws = (char*)d_ws;
    size_t off = 0;
    auto alloc = [&](size_t bytes) -> char* {
        char* p = ws + off;
        off += (bytes + 255) / 256 * 256;
        return p;
    };
    const int N = NNODES, E = NEDGES;
    float* H        = (float*)alloc((size_t)N * 128 * 4);
    float* A        = (float*)alloc((size_t)N * 128 * 4);
    float* dinv     = (float*)alloc((size_t)N * 4);      // deg accumulator, then dinv
    float* selfn    = (float*)alloc((size_t)N * 4);
    int*   cnt      = (int*)alloc((size_t)N * 4);
    int*   cursor   = (int*)alloc((size_t)N * 4);
    int*   row_start= (int*)alloc((size_t)(N + 1) * 4);
    int*   csr_src  = (int*)alloc((size_t)E * 4);
    float* csr_w    = (float*)alloc((size_t)E * 4);
    float* gstats   = (float*)alloc(256 * 4);            // gsum[128] | gss[128]
    float* gsum = gstats, *gss = gstats + 128;
    float* pooled   = (float*)alloc(64 * 128 * 4);
    float* pooled2  = (float*)alloc(64 * 128 * 4);

    const int nblk = (N + 255) / 256;    // 196
    const int eblk = (E + 255) / 256;    // 3125

    // --- graph structure (shared across all 3 convs) ---
    init_kernel<<<nblk, 256, 0, stream>>>(dinv, cnt, cursor, N);
    deg_kernel<<<eblk, 256, 0, stream>>>(ei, ew, dinv, E);
    dinv_kernel<<<nblk, 256, 0, stream>>>(dinv, selfn, N);
    count_kernel<<<eblk, 256, 0, stream>>>(ei, cnt, E);
    scan_kernel<<<1, 1024, 0, stream>>>(cnt, row_start, N);
    fill_kernel<<<eblk, 256, 0, stream>>>(ei, ew, dinv, row_start, cursor, csr_src, csr_w, E);

    const int gemmblk = (N + 127) / 128;         // 391
    const int aggblk  = (N + 1) / 2;             // 25000
    const int ewblk   = (N * 128) / 256;         // 25000

    // --- layer 1 ---
    gemm_x128<<<gemmblk, 256, 0, stream>>>(x, W1, H, N);
    agg_kernel<<<aggblk, 256, 0, stream>>>(H, row_start, csr_src, csr_w, selfn, b1, A, N);
    hipMemsetAsync(gstats, 0, 256 * 4, stream);
    stats_kernel<<<256, 256, 0, stream>>>(A, gsum, gss, N);
    bnrelu_kernel<<<ewblk, 256, 0, stream>>>(A, gsum, gss, g1, bt1, H, N);

    // --- layer 2 ---
    gemm_x128<<<gemmblk, 256, 0, stream>>>(H, W2, A, N);
    agg_kernel<<<aggblk, 256, 0, stream>>>(A, row_start, csr_src, csr_w, selfn, b2, H, N);
    hipMemsetAsync(gstats, 0, 256 * 4, stream);
    stats_kernel<<<256, 256, 0, stream>>>(H, gsum, gss, N);
    bnrelu_kernel<<<ewblk, 256, 0, stream>>>(H, gsum, gss, g2, bt2, A, N);

    // --- layer 3 (BN uses g2/bt2 per reference bug) ---
    gemm_x128<<<gemmblk, 256, 0, stream>>>(A, W3, H, N);
    agg_kernel<<<aggblk, 256, 0, stream>>>(H, row_start, csr_src, csr_w, selfn, b3, A, N);
    hipMemsetAsync(gstats, 0, 256 * 4, stream);
    stats_kernel<<<256, 256, 0, stream>>>(A, gsum, gss, N);
    bnrelu_kernel<<<ewblk, 256, 0, stream>>>(A, gsum, gss, g2, bt2, H, N);

    // --- pool + head ---
    hipMemsetAsync(pooled, 0, 64 * 128 * 4, stream);
    pool_kernel<<<NGRAPHS * 8, 128, 0, stream>>>(H, batch, pooled, N);
    head1_kernel<<<NGRAPHS, 128, 0, stream>>>(pooled, Wn, bnb, pooled2);
    head2_kernel<<<NGRAPHS, 64, 0, stream>>>(pooled2, Wf, bf, out);
}

// Round 3
// 579.869 us; speedup vs baseline: 1.7449x; 1.7449x over previous
//
#include <hip/hip_runtime.h>

#define NNODES 50000
#define NEDGES 800000
#define NGRAPHS 64
#define NCLASSES 38
#define EPSBN 1e-5f

typedef __attribute__((ext_vector_type(8))) short bf16x8;
typedef __attribute__((ext_vector_type(4))) float f32x4;

__device__ __forceinline__ float bflo(unsigned u) { return __uint_as_float(u << 16); }
__device__ __forceinline__ float bfhi(unsigned u) { return __uint_as_float(u & 0xffff0000u); }
__device__ __forceinline__ unsigned short f2bf(float f) {
    unsigned u = __float_as_uint(f);
    return (unsigned short)((u + 0x7fffu + ((u >> 16) & 1u)) >> 16);
}

// ---------------- graph preprocessing ----------------

__global__ void init_kernel(float* deg, int* cnt, int* cursor, int N) {
    int i = blockIdx.x * blockDim.x + threadIdx.x;
    if (i < N) { deg[i] = 0.f; cnt[i] = 0; cursor[i] = 0; }
}

__global__ void degcount_kernel(const int* __restrict__ ei, const float* __restrict__ ew,
                                float* deg, int* cnt, int E) {
    int e = blockIdx.x * blockDim.x + threadIdx.x;
    if (e < E) {
        int d = ei[E + e];
        atomicAdd(&deg[d], ew[e]);
        atomicAdd(&cnt[d], 1);
    }
}

__global__ void dinv_kernel(float* deg_dinv, float* selfn, int N) {
    int i = blockIdx.x * blockDim.x + threadIdx.x;
    if (i < N) {
        float d = deg_dinv[i] + 1.0f;           // +1 for self-loop weight
        float di = rsqrtf(fmaxf(d, 1e-12f));
        deg_dinv[i] = di;
        selfn[i] = di * di;
    }
}

__global__ __launch_bounds__(1024) void scan_kernel(const int* __restrict__ cnt,
                                                    int* __restrict__ row_start, int N) {
    __shared__ int part[1024];
    int t = threadIdx.x;
    int CH = (N + 1023) >> 10;
    int base = t * CH;
    int s = 0;
    for (int i = 0; i < CH; i++) { int idx = base + i; if (idx < N) s += cnt[idx]; }
    part[t] = s;
    __syncthreads();
    for (int o = 1; o < 1024; o <<= 1) {
        int v = (t >= o) ? part[t - o] : 0;
        __syncthreads();
        part[t] += v;
        __syncthreads();
    }
    int run = (t > 0) ? part[t - 1] : 0;
    for (int i = 0; i < CH; i++) {
        int idx = base + i;
        if (idx < N) { row_start[idx] = run; run += cnt[idx]; }
    }
    if (t == 0) row_start[N] = part[1023];
}

__global__ void fill_kernel(const int* __restrict__ ei, const float* __restrict__ ew,
                            const float* __restrict__ dinv, const int* __restrict__ row_start,
                            int* cursor, int* __restrict__ csr_src, float* __restrict__ csr_w,
                            int E) {
    int e = blockIdx.x * blockDim.x + threadIdx.x;
    if (e >= E) return;
    int s = ei[e], d = ei[E + e];
    int slot = row_start[d] + atomicAdd(&cursor[d], 1);
    csr_src[slot] = s;
    csr_w[slot] = dinv[s] * ew[e] * dinv[d];
}

// W [k=128][c=128] fp32 -> Wt [c][k] bf16
__global__ void wcast_kernel(const float* __restrict__ W, unsigned short* __restrict__ Wt) {
    int idx = blockIdx.x * 256 + threadIdx.x;   // 0..16383
    int c = idx >> 7, k = idx & 127;
    Wt[c * 128 + k] = f2bf(W[k * 128 + c]);
}

// ---------------- MFMA GEMM: [M,128] @ [128,128] -> bf16 [M,128] ----------------
// optionally fuses y = relu(x*scale[k]+shift[k]) on the bf16 input (BN of previous layer)

template <bool IN_F32, bool FUSE_BN>
__global__ __launch_bounds__(256) void gemm_mfma(const void* __restrict__ Xin,
                                                 const unsigned short* __restrict__ Wt,
                                                 const float* __restrict__ scale,
                                                 const float* __restrict__ shift,
                                                 unsigned short* __restrict__ Hout, int M) {
    __shared__ unsigned short tile[128 * 128];
    const int lane = threadIdx.x & 63;
    const int wave = threadIdx.x >> 6;
    const int lr = lane & 15;
    const int lk = lane >> 4;     // 0..3
    const int row0 = blockIdx.x * 128 + wave * 32;

    f32x4 zero = {0.f, 0.f, 0.f, 0.f};
    f32x4 acc[2][8];
#pragma unroll
    for (int m = 0; m < 2; m++)
#pragma unroll
        for (int n = 0; n < 8; n++) acc[m][n] = zero;

#pragma unroll
    for (int ks = 0; ks < 4; ++ks) {
        const int kb = ks * 32 + lk * 8;
        bf16x8 a[2];
#pragma unroll
        for (int m = 0; m < 2; ++m) {
            union { bf16x8 v; unsigned short u[8]; uint4 q; } ua;
            int r = row0 + m * 16 + lr;
            if (r < M) {
                if (IN_F32) {
                    const float* X = (const float*)Xin;
                    float4 x0 = *reinterpret_cast<const float4*>(&X[(size_t)r * 128 + kb]);
                    float4 x1 = *reinterpret_cast<const float4*>(&X[(size_t)r * 128 + kb + 4]);
                    ua.u[0] = f2bf(x0.x); ua.u[1] = f2bf(x0.y); ua.u[2] = f2bf(x0.z); ua.u[3] = f2bf(x0.w);
                    ua.u[4] = f2bf(x1.x); ua.u[5] = f2bf(x1.y); ua.u[6] = f2bf(x1.z); ua.u[7] = f2bf(x1.w);
                } else {
                    const unsigned short* X = (const unsigned short*)Xin;
                    uint4 q = *reinterpret_cast<const uint4*>(&X[(size_t)r * 128 + kb]);
                    if (FUSE_BN) {
                        unsigned qq[4] = {q.x, q.y, q.z, q.w};
#pragma unroll
                        for (int i = 0; i < 4; i++) {
                            float y0 = fmaxf(bflo(qq[i]) * scale[kb + 2 * i] + shift[kb + 2 * i], 0.f);
                            float y1 = fmaxf(bfhi(qq[i]) * scale[kb + 2 * i + 1] + shift[kb + 2 * i + 1], 0.f);
                            ua.u[2 * i] = f2bf(y0);
                            ua.u[2 * i + 1] = f2bf(y1);
                        }
                    } else {
                        ua.q = q;
                    }
                }
            } else {
                ua.q = make_uint4(0, 0, 0, 0);
            }
            a[m] = ua.v;
        }
        bf16x8 b[8];
#pragma unroll
        for (int n = 0; n < 8; ++n) {
            union { bf16x8 v; uint4 q; } ub;
            ub.q = *reinterpret_cast<const uint4*>(&Wt[(size_t)(n * 16 + lr) * 128 + kb]);
            b[n] = ub.v;
        }
#pragma unroll
        for (int m = 0; m < 2; ++m)
#pragma unroll
            for (int n = 0; n < 8; ++n)
                acc[m][n] = __builtin_amdgcn_mfma_f32_16x16x32_bf16(a[m], b[n], acc[m][n], 0, 0, 0);
    }

    // epilogue: C/D layout col=lane&15, row=(lane>>4)*4+reg  -> repack via LDS, 16B stores
#pragma unroll
    for (int m = 0; m < 2; ++m)
#pragma unroll
        for (int n = 0; n < 8; ++n)
#pragma unroll
            for (int r = 0; r < 4; ++r) {
                int rl = wave * 32 + m * 16 + lk * 4 + r;
                int c = n * 16 + lr;
                tile[rl * 128 + c] = f2bf(acc[m][n][r]);
            }
    __syncthreads();
#pragma unroll
    for (int it = 0; it < 8; ++it) {
        int idx = threadIdx.x + it * 256;     // 2048 16B-chunks
        int r = idx >> 4, c8 = (idx & 15) * 8;
        int gr = blockIdx.x * 128 + r;
        if (gr < M)
            *reinterpret_cast<uint4*>(&Hout[(size_t)gr * 128 + c8]) =
                *reinterpret_cast<const uint4*>(&tile[r * 128 + c8]);
    }
}

// ---------------- aggregation (bf16 rows, fp32 accum) ----------------

__device__ __forceinline__ void acc8(float* acc, uint4 v, float w) {
    unsigned q0 = v.x, q1 = v.y, q2 = v.z, q3 = v.w;
    acc[0] += w * bflo(q0); acc[1] += w * bfhi(q0);
    acc[2] += w * bflo(q1); acc[3] += w * bfhi(q1);
    acc[4] += w * bflo(q2); acc[5] += w * bfhi(q2);
    acc[6] += w * bflo(q3); acc[7] += w * bfhi(q3);
}

__global__ __launch_bounds__(256) void agg_kernel(const unsigned short* __restrict__ Hb,
                                                  const int* __restrict__ row_start,
                                                  const int* __restrict__ csr_src,
                                                  const float* __restrict__ csr_w,
                                                  const float* __restrict__ selfn,
                                                  const float* __restrict__ bias,
                                                  unsigned short* __restrict__ Ab, int N) {
    int node = blockIdx.x * 16 + (threadIdx.x >> 4);
    int fb = (threadIdx.x & 15) * 8;
    if (node >= N) return;
    float acc[8];
    uint4 hv = *reinterpret_cast<const uint4*>(&Hb[(size_t)node * 128 + fb]);
    float sn = selfn[node];
    {
        unsigned q[4] = {hv.x, hv.y, hv.z, hv.w};
#pragma unroll
        for (int i = 0; i < 4; i++) {
            acc[2 * i] = sn * bflo(q[i]) + bias[fb + 2 * i];
            acc[2 * i + 1] = sn * bfhi(q[i]) + bias[fb + 2 * i + 1];
        }
    }
    int e0 = row_start[node], e1 = row_start[node + 1];
    int j = e0;
    for (; j + 4 <= e1; j += 4) {
        int s0 = csr_src[j], s1 = csr_src[j + 1], s2 = csr_src[j + 2], s3 = csr_src[j + 3];
        float w0 = csr_w[j], w1 = csr_w[j + 1], w2 = csr_w[j + 2], w3 = csr_w[j + 3];
        uint4 v0 = *reinterpret_cast<const uint4*>(&Hb[(size_t)s0 * 128 + fb]);
        uint4 v1 = *reinterpret_cast<const uint4*>(&Hb[(size_t)s1 * 128 + fb]);
        uint4 v2 = *reinterpret_cast<const uint4*>(&Hb[(size_t)s2 * 128 + fb]);
        uint4 v3 = *reinterpret_cast<const uint4*>(&Hb[(size_t)s3 * 128 + fb]);
        acc8(acc, v0, w0); acc8(acc, v1, w1); acc8(acc, v2, w2); acc8(acc, v3, w3);
    }
    for (; j < e1; ++j) {
        int s = csr_src[j];
        float w = csr_w[j];
        uint4 v = *reinterpret_cast<const uint4*>(&Hb[(size_t)s * 128 + fb]);
        acc8(acc, v, w);
    }
    uint4 o;
    o.x = (unsigned)f2bf(acc[0]) | ((unsigned)f2bf(acc[1]) << 16);
    o.y = (unsigned)f2bf(acc[2]) | ((unsigned)f2bf(acc[3]) << 16);
    o.z = (unsigned)f2bf(acc[4]) | ((unsigned)f2bf(acc[5]) << 16);
    o.w = (unsigned)f2bf(acc[6]) | ((unsigned)f2bf(acc[7]) << 16);
    *reinterpret_cast<uint4*>(&Ab[(size_t)node * 128 + fb]) = o;
}

// ---------------- BN stats (bf16 input) + finalize ----------------

__global__ __launch_bounds__(256) void stats_bf16(const unsigned short* __restrict__ A,
                                                  float* __restrict__ gsum,
                                                  float* __restrict__ gss, int N) {
    const int f8 = threadIdx.x & 15;
    const int rg = threadIdx.x >> 4;    // 0..15
    float s[8], ss[8];
#pragma unroll
    for (int i = 0; i < 8; i++) { s[i] = 0.f; ss[i] = 0.f; }
    for (int r = blockIdx.x * 16 + rg; r < N; r += gridDim.x * 16) {
        uint4 v = *reinterpret_cast<const uint4*>(&A[(size_t)r * 128 + f8 * 8]);
        unsigned q[4] = {v.x, v.y, v.z, v.w};
#pragma unroll
        for (int i = 0; i < 4; i++) {
            float a = bflo(q[i]), b = bfhi(q[i]);
            s[2 * i] += a; ss[2 * i] += a * a;
            s[2 * i + 1] += b; ss[2 * i + 1] += b * b;
        }
    }
    __shared__ float shs[256 * 8];
    __shared__ float shq[256 * 8];
#pragma unroll
    for (int i = 0; i < 8; i++) {
        shs[rg * 128 + f8 * 8 + i] = s[i];
        shq[rg * 128 + f8 * 8 + i] = ss[i];
    }
    __syncthreads();
    for (int off = 8; off >= 1; off >>= 1) {
        if (rg < off) {
#pragma unroll
            for (int i = 0; i < 8; i++) {
                shs[rg * 128 + f8 * 8 + i] += shs[(rg + off) * 128 + f8 * 8 + i];
                shq[rg * 128 + f8 * 8 + i] += shq[(rg + off) * 128 + f8 * 8 + i];
            }
        }
        __syncthreads();
    }
    if (rg == 0) {
#pragma unroll
        for (int i = 0; i < 8; i++) {
            atomicAdd(&gsum[f8 * 8 + i], shs[f8 * 8 + i]);
            atomicAdd(&gss[f8 * 8 + i], shq[f8 * 8 + i]);
        }
    }
}

__global__ void finalize_kernel(const float* __restrict__ gsum, const float* __restrict__ gss,
                                const float* __restrict__ g, const float* __restrict__ bt,
                                float* __restrict__ scale, float* __restrict__ shift, int N) {
    int f = threadIdx.x;
    float invn = 1.0f / (float)N;
    float m = gsum[f] * invn;
    float var = gss[f] * invn - m * m;
    float s = rsqrtf(var + EPSBN) * g[f];
    scale[f] = s;
    shift[f] = bt[f] - m * s;
}

// ---------------- pooling (BN+ReLU fused) + head ----------------

__device__ __forceinline__ int lower_bound_dev(const int* arr, int n, int key) {
    int lo = 0, hi = n;
    while (lo < hi) {
        int mid = (lo + hi) >> 1;
        if (arr[mid] < key) lo = mid + 1; else hi = mid;
    }
    return lo;
}

__global__ __launch_bounds__(128) void pool_bn_kernel(const unsigned short* __restrict__ A,
                                                      const float* __restrict__ scale,
                                                      const float* __restrict__ shift,
                                                      const int* __restrict__ batch,
                                                      float* __restrict__ pooled, int N) {
    int g = blockIdx.x >> 3, chunk = blockIdx.x & 7;
    int start = lower_bound_dev(batch, N, g);
    int end = lower_bound_dev(batch, N, g + 1);
    long long len = end - start;
    int c0 = start + (int)(len * chunk / 8);
    int c1 = start + (int)(len * (chunk + 1) / 8);
    int f = threadIdx.x;
    float sc = scale[f], sh = shift[f];
    float acc = 0.f;
    for (int r = c0; r < c1; ++r) {
        float v = __uint_as_float(((unsigned)A[(size_t)r * 128 + f]) << 16);
        acc += fmaxf(v * sc + sh, 0.f);
    }
    atomicAdd(&pooled[g * 128 + f], acc);
}

__global__ __launch_bounds__(128) void head1_kernel(const float* __restrict__ pooled,
                                                    const float* __restrict__ Wn,
                                                    const float* __restrict__ bnb,
                                                    float* __restrict__ p2) {
    int g = blockIdx.x, f = threadIdx.x;
    __shared__ float row[128];
    row[f] = pooled[g * 128 + f];
    __syncthreads();
    float acc = bnb[f];
    for (int k = 0; k < 128; k++) acc += row[k] * Wn[k * 128 + f];
    p2[g * 128 + f] = acc;
}

__global__ __launch_bounds__(64) void head2_kernel(const float* __restrict__ p2,
                                                   const float* __restrict__ Wf,
                                                   const float* __restrict__ bf,
                                                   float* __restrict__ out) {
    int g = blockIdx.x, t = threadIdx.x;
    __shared__ float row[128];
    row[t] = p2[g * 128 + t];
    row[t + 64] = p2[g * 128 + 64 + t];
    __syncthreads();
    float acc = -1e30f;
    if (t < NCLASSES) {
        acc = bf[t];
        for (int k = 0; k < 128; k++) acc += row[k] * Wf[k * NCLASSES + t];
    }
    float m = acc;
    for (int o = 32; o > 0; o >>= 1) m = fmaxf(m, __shfl_xor(m, o));
    float e = (t < NCLASSES) ? expf(acc - m) : 0.f;
    float ssum = e;
    for (int o = 32; o > 0; o >>= 1) ssum += __shfl_xor(ssum, o);
    if (t < NCLASSES) out[g * NCLASSES + t] = acc - m - logf(ssum);
}

// ---------------- launch ----------------

extern "C" void kernel_launch(void* const* d_in, const int* in_sizes, int n_in,
                              void* d_out, int out_size, void* d_ws, size_t ws_size,
                              hipStream_t stream) {
    const float* x    = (const float*)d_in[0];
    const int*   ei   = (const int*)d_in[1];
    const float* ew   = (const float*)d_in[2];
    const int*   batch= (const int*)d_in[3];
    const float* W1   = (const float*)d_in[4];
    const float* b1   = (const float*)d_in[5];
    const float* g1   = (const float*)d_in[6];
    const float* bt1  = (const float*)d_in[7];
    const float* W2   = (const float*)d_in[8];
    const float* b2   = (const float*)d_in[9];
    const float* g2   = (const float*)d_in[10];
    const float* bt2  = (const float*)d_in[11];
    const float* W3   = (const float*)d_in[12];
    const float* b3   = (const float*)d_in[13];
    const float* Wn   = (const float*)d_in[14];
    const float* bnb  = (const float*)d_in[15];
    const float* Wf   = (const float*)d_in[16];
    const float* bf   = (const float*)d_in[17];
    float* out = (float*)d_out;
    (void)in_sizes; (void)n_in; (void)out_size; (void)ws_size;

    char* ws = (char*)d_ws;
    size_t off = 0;
    auto alloc = [&](size_t bytes) -> char* {
        char* p = ws + off;
        off += (bytes + 255) / 256 * 256;
        return p;
    };
    const int N = NNODES, E = NEDGES;
    unsigned short* Hb = (unsigned short*)alloc((size_t)N * 128 * 2);
    unsigned short* Ab = (unsigned short*)alloc((size_t)N * 128 * 2);
    float* dinv      = (float*)alloc((size_t)N * 4);
    float* selfn     = (float*)alloc((size_t)N * 4);
    int*   cnt       = (int*)alloc((size_t)N * 4);
    int*   cursor    = (int*)alloc((size_t)N * 4);
    int*   row_start = (int*)alloc((size_t)(N + 1) * 4);
    int*   csr_src   = (int*)alloc((size_t)E * 4);
    float* csr_w     = (float*)alloc((size_t)E * 4);
    float* gstats    = (float*)alloc(256 * 4);
    float* gsum = gstats, *gss = gstats + 128;
    float* scaleB    = (float*)alloc(128 * 4);
    float* shiftB    = (float*)alloc(128 * 4);
    unsigned short* Wt1 = (unsigned short*)alloc(16384 * 2);
    unsigned short* Wt2 = (unsigned short*)alloc(16384 * 2);
    unsigned short* Wt3 = (unsigned short*)alloc(16384 * 2);
    float* pooled    = (float*)alloc(64 * 128 * 4);
    float* pooled2   = (float*)alloc(64 * 128 * 4);

    const int nblk = (N + 255) / 256;
    const int eblk = (E + 255) / 256;
    const int gemmblk = (N + 127) / 128;       // 391
    const int aggblk = (N + 15) / 16;          // 3125

    // graph structure (shared by all 3 convs)
    init_kernel<<<nblk, 256, 0, stream>>>(dinv, cnt, cursor, N);
    degcount_kernel<<<eblk, 256, 0, stream>>>(ei, ew, dinv, cnt, E);
    dinv_kernel<<<nblk, 256, 0, stream>>>(dinv, selfn, N);
    scan_kernel<<<1, 1024, 0, stream>>>(cnt, row_start, N);
    fill_kernel<<<eblk, 256, 0, stream>>>(ei, ew, dinv, row_start, cursor, csr_src, csr_w, E);
    wcast_kernel<<<64, 256, 0, stream>>>(W1, Wt1);
    wcast_kernel<<<64, 256, 0, stream>>>(W2, Wt2);
    wcast_kernel<<<64, 256, 0, stream>>>(W3, Wt3);

    // --- layer 1 ---
    gemm_mfma<true, false><<<gemmblk, 256, 0, stream>>>(x, Wt1, nullptr, nullptr, Hb, N);
    agg_kernel<<<aggblk, 256, 0, stream>>>(Hb, row_start, csr_src, csr_w, selfn, b1, Ab, N);
    (void)hipMemsetAsync(gstats, 0, 256 * 4, stream);
    stats_bf16<<<256, 256, 0, stream>>>(Ab, gsum, gss, N);
    finalize_kernel<<<1, 128, 0, stream>>>(gsum, gss, g1, bt1, scaleB, shiftB, N);

    // --- layer 2 (BN1+ReLU fused into GEMM A-load) ---
    gemm_mfma<false, true><<<gemmblk, 256, 0, stream>>>(Ab, Wt2, scaleB, shiftB, Hb, N);
    agg_kernel<<<aggblk, 256, 0, stream>>>(Hb, row_start, csr_src, csr_w, selfn, b2, Ab, N);
    (void)hipMemsetAsync(gstats, 0, 256 * 4, stream);
    stats_bf16<<<256, 256, 0, stream>>>(Ab, gsum, gss, N);
    finalize_kernel<<<1, 128, 0, stream>>>(gsum, gss, g2, bt2, scaleB, shiftB, N);

    // --- layer 3 (BN2+ReLU fused into GEMM A-load; layer-3 BN uses g2/bt2 per reference bug) ---
    gemm_mfma<false, true><<<gemmblk, 256, 0, stream>>>(Ab, Wt3, scaleB, shiftB, Hb, N);
    agg_kernel<<<aggblk, 256, 0, stream>>>(Hb, row_start, csr_src, csr_w, selfn, b3, Ab, N);
    (void)hipMemsetAsync(gstats, 0, 256 * 4, stream);
    stats_bf16<<<256, 256, 0, stream>>>(Ab, gsum, gss, N);
    finalize_kernel<<<1, 128, 0, stream>>>(gsum, gss, g2, bt2, scaleB, shiftB, N);

    // --- pool (BN3+ReLU fused) + head ---
    (void)hipMemsetAsync(pooled, 0, 64 * 128 * 4, stream);
    pool_bn_kernel<<<NGRAPHS * 8, 128, 0, stream>>>(Ab, scaleB, shiftB, batch, pooled, N);
    head1_kernel<<<NGRAPHS, 128, 0, stream>>>(pooled, Wn, bnb, pooled2);
    head2_kernel<<<NGRAPHS, 64, 0, stream>>>(pooled2, Wf, bf, out);
}

// Round 4
// 490.899 us; speedup vs baseline: 2.0612x; 1.1812x over previous
//
#include <hip/hip_runtime.h>

#define NNODES 50000
#define NEDGES 800000
#define NGRAPHS 64
#define NCLASSES 38
#define EPSBN 1e-5f
#define SCAN_NB 196   // ceil(50000/256)

typedef __attribute__((ext_vector_type(8))) short bf16x8;
typedef __attribute__((ext_vector_type(4))) float f32x4;

__device__ __forceinline__ float bflo(unsigned u) { return __uint_as_float(u << 16); }
__device__ __forceinline__ float bfhi(unsigned u) { return __uint_as_float(u & 0xffff0000u); }
__device__ __forceinline__ unsigned short f2bf(float f) {
    unsigned u = __float_as_uint(f);
    return (unsigned short)((u + 0x7fffu + ((u >> 16) & 1u)) >> 16);
}

// ---------------- graph preprocessing ----------------

__global__ void degcount_kernel(const int* __restrict__ ei, const float* __restrict__ ew,
                                float* deg, int* cnt, int E) {
    int e = blockIdx.x * blockDim.x + threadIdx.x;
    if (e < E) {
        int d = ei[E + e];
        atomicAdd(&deg[d], ew[e]);
        atomicAdd(&cnt[d], 1);
    }
}

// dinv/selfn from deg, plus per-block sum of cnt (stage A of scan)
__global__ __launch_bounds__(256) void dinv_bsum_kernel(float* deg_dinv, float* selfn,
                                                        const int* __restrict__ cnt,
                                                        int* __restrict__ bsum, int N) {
    int i = blockIdx.x * 256 + threadIdx.x;
    if (i < N) {
        float d = deg_dinv[i] + 1.0f;           // +1 self-loop weight
        float di = rsqrtf(fmaxf(d, 1e-12f));
        deg_dinv[i] = di;
        selfn[i] = di * di;
    }
    int v = (i < N) ? cnt[i] : 0;
#pragma unroll
    for (int o = 1; o < 64; o <<= 1) v += __shfl_xor(v, o, 64);
    __shared__ int ws[4];
    int lane = threadIdx.x & 63, w = threadIdx.x >> 6;
    if (lane == 0) ws[w] = v;
    __syncthreads();
    if (threadIdx.x == 0) bsum[blockIdx.x] = ws[0] + ws[1] + ws[2] + ws[3];
}

// stage B: exclusive scan of the <=256 block sums; also writes row_start[N]=total
__global__ __launch_bounds__(256) void scan_bsum_kernel(const int* __restrict__ bsum,
                                                        int* __restrict__ bofs,
                                                        int* __restrict__ row_start, int NB, int N) {
    int t = threadIdx.x;
    int v = (t < NB) ? bsum[t] : 0;
    int lane = t & 63, w = t >> 6;
    int s = v;
#pragma unroll
    for (int o = 1; o < 64; o <<= 1) { int u = __shfl_up(s, o, 64); if (lane >= o) s += u; }
    __shared__ int wsum[4];
    if (lane == 63) wsum[w] = s;
    __syncthreads();
    int wofs = 0;
    for (int k = 0; k < w; k++) wofs += wsum[k];
    if (t < NB) bofs[t] = wofs + s - v;
    if (t == 255) row_start[N] = wofs + s;
}

// stage C: per-block exclusive scan + block offset -> row_start
__global__ __launch_bounds__(256) void scan_fin_kernel(const int* __restrict__ cnt,
                                                       const int* __restrict__ bofs,
                                                       int* __restrict__ row_start, int N) {
    int i = blockIdx.x * 256 + threadIdx.x;
    int v = (i < N) ? cnt[i] : 0;
    int lane = threadIdx.x & 63, w = threadIdx.x >> 6;
    int s = v;
#pragma unroll
    for (int o = 1; o < 64; o <<= 1) { int u = __shfl_up(s, o, 64); if (lane >= o) s += u; }
    __shared__ int wsum[4];
    if (lane == 63) wsum[w] = s;
    __syncthreads();
    int wofs = 0;
    for (int k = 0; k < w; k++) wofs += wsum[k];
    if (i < N) row_start[i] = bofs[blockIdx.x] + wofs + s - v;
}

__global__ void fill_kernel(const int* __restrict__ ei, const float* __restrict__ ew,
                            const float* __restrict__ dinv, const int* __restrict__ row_start,
                            int* cursor, uint2* __restrict__ csr, int E) {
    int e = blockIdx.x * blockDim.x + threadIdx.x;
    if (e >= E) return;
    int s = ei[e], d = ei[E + e];
    int slot = row_start[d] + atomicAdd(&cursor[d], 1);
    uint2 p;
    p.x = (unsigned)s;
    p.y = __float_as_uint(dinv[s] * ew[e] * dinv[d]);
    csr[slot] = p;
}

// all three W [k][c] fp32 -> Wt [c][k] bf16 in one launch
__global__ void wcast3_kernel(const float* __restrict__ W1, const float* __restrict__ W2,
                              const float* __restrict__ W3, unsigned short* __restrict__ Wt) {
    int idx = blockIdx.x * 256 + threadIdx.x;   // 0..49151
    int which = idx >> 14;
    int r = idx & 16383;
    const float* W = which == 0 ? W1 : (which == 1 ? W2 : W3);
    int c = r >> 7, k = r & 127;
    Wt[which * 16384 + c * 128 + k] = f2bf(W[k * 128 + c]);
}

// ---------------- MFMA GEMM: [M,128] @ [128,128] -> bf16 [M,128] ----------------
// optionally fuses y = relu(x*scale[k]+shift[k]) on the bf16 input (BN of previous layer)

template <bool IN_F32, bool FUSE_BN>
__global__ __launch_bounds__(256) void gemm_mfma(const void* __restrict__ Xin,
                                                 const unsigned short* __restrict__ Wt,
                                                 const float* __restrict__ scale,
                                                 const float* __restrict__ shift,
                                                 unsigned short* __restrict__ Hout, int M) {
    __shared__ unsigned short tile[128 * 128];
    const int lane = threadIdx.x & 63;
    const int wave = threadIdx.x >> 6;
    const int lr = lane & 15;
    const int lk = lane >> 4;     // 0..3
    const int row0 = blockIdx.x * 128 + wave * 32;

    f32x4 zero = {0.f, 0.f, 0.f, 0.f};
    f32x4 acc[2][8];
#pragma unroll
    for (int m = 0; m < 2; m++)
#pragma unroll
        for (int n = 0; n < 8; n++) acc[m][n] = zero;

#pragma unroll
    for (int ks = 0; ks < 4; ++ks) {
        const int kb = ks * 32 + lk * 8;
        bf16x8 a[2];
#pragma unroll
        for (int m = 0; m < 2; ++m) {
            union { bf16x8 v; unsigned short u[8]; uint4 q; } ua;
            int r = row0 + m * 16 + lr;
            if (r < M) {
                if (IN_F32) {
                    const float* X = (const float*)Xin;
                    float4 x0 = *reinterpret_cast<const float4*>(&X[(size_t)r * 128 + kb]);
                    float4 x1 = *reinterpret_cast<const float4*>(&X[(size_t)r * 128 + kb + 4]);
                    ua.u[0] = f2bf(x0.x); ua.u[1] = f2bf(x0.y); ua.u[2] = f2bf(x0.z); ua.u[3] = f2bf(x0.w);
                    ua.u[4] = f2bf(x1.x); ua.u[5] = f2bf(x1.y); ua.u[6] = f2bf(x1.z); ua.u[7] = f2bf(x1.w);
                } else {
                    const unsigned short* X = (const unsigned short*)Xin;
                    uint4 q = *reinterpret_cast<const uint4*>(&X[(size_t)r * 128 + kb]);
                    if (FUSE_BN) {
                        unsigned qq[4] = {q.x, q.y, q.z, q.w};
#pragma unroll
                        for (int i = 0; i < 4; i++) {
                            float y0 = fmaxf(bflo(qq[i]) * scale[kb + 2 * i] + shift[kb + 2 * i], 0.f);
                            float y1 = fmaxf(bfhi(qq[i]) * scale[kb + 2 * i + 1] + shift[kb + 2 * i + 1], 0.f);
                            ua.u[2 * i] = f2bf(y0);
                            ua.u[2 * i + 1] = f2bf(y1);
                        }
                    } else {
                        ua.q = q;
                    }
                }
            } else {
                ua.q = make_uint4(0, 0, 0, 0);
            }
            a[m] = ua.v;
        }
        bf16x8 b[8];
#pragma unroll
        for (int n = 0; n < 8; ++n) {
            union { bf16x8 v; uint4 q; } ub;
            ub.q = *reinterpret_cast<const uint4*>(&Wt[(size_t)(n * 16 + lr) * 128 + kb]);
            b[n] = ub.v;
        }
#pragma unroll
        for (int m = 0; m < 2; ++m)
#pragma unroll
            for (int n = 0; n < 8; ++n)
                acc[m][n] = __builtin_amdgcn_mfma_f32_16x16x32_bf16(a[m], b[n], acc[m][n], 0, 0, 0);
    }

    // epilogue: C/D layout col=lane&15, row=(lane>>4)*4+reg -> repack via LDS, 16B stores
#pragma unroll
    for (int m = 0; m < 2; ++m)
#pragma unroll
        for (int n = 0; n < 8; ++n)
#pragma unroll
            for (int r = 0; r < 4; ++r) {
                int rl = wave * 32 + m * 16 + lk * 4 + r;
                int c = n * 16 + lr;
                tile[rl * 128 + c] = f2bf(acc[m][n][r]);
            }
    __syncthreads();
#pragma unroll
    for (int it = 0; it < 8; ++it) {
        int idx = threadIdx.x + it * 256;     // 2048 16B-chunks
        int r = idx >> 4, c8 = (idx & 15) * 8;
        int gr = blockIdx.x * 128 + r;
        if (gr < M)
            *reinterpret_cast<uint4*>(&Hout[(size_t)gr * 128 + c8]) =
                *reinterpret_cast<const uint4*>(&tile[r * 128 + c8]);
    }
}

// ---------------- aggregation (bf16 rows, fp32 accum) ----------------

__device__ __forceinline__ void acc8(float* acc, uint4 v, float w) {
    unsigned q0 = v.x, q1 = v.y, q2 = v.z, q3 = v.w;
    acc[0] += w * bflo(q0); acc[1] += w * bfhi(q0);
    acc[2] += w * bflo(q1); acc[3] += w * bfhi(q1);
    acc[4] += w * bflo(q2); acc[5] += w * bfhi(q2);
    acc[6] += w * bflo(q3); acc[7] += w * bfhi(q3);
}

__global__ __launch_bounds__(256) void agg_kernel(const unsigned short* __restrict__ Hb,
                                                  const int* __restrict__ row_start,
                                                  const uint2* __restrict__ csr,
                                                  const float* __restrict__ selfn,
                                                  const float* __restrict__ bias,
                                                  unsigned short* __restrict__ Ab, int N) {
    int node = blockIdx.x * 16 + (threadIdx.x >> 4);
    int fb = (threadIdx.x & 15) * 8;
    if (node >= N) return;
    float acc[8];
    uint4 hv = *reinterpret_cast<const uint4*>(&Hb[(size_t)node * 128 + fb]);
    float sn = selfn[node];
    {
        unsigned q[4] = {hv.x, hv.y, hv.z, hv.w};
#pragma unroll
        for (int i = 0; i < 4; i++) {
            acc[2 * i] = sn * bflo(q[i]) + bias[fb + 2 * i];
            acc[2 * i + 1] = sn * bfhi(q[i]) + bias[fb + 2 * i + 1];
        }
    }
    int e0 = row_start[node], e1 = row_start[node + 1];
    int j = e0;
    for (; j + 4 <= e1; j += 4) {
        uint2 p0 = csr[j], p1 = csr[j + 1], p2 = csr[j + 2], p3 = csr[j + 3];
        uint4 v0 = *reinterpret_cast<const uint4*>(&Hb[(size_t)p0.x * 128 + fb]);
        uint4 v1 = *reinterpret_cast<const uint4*>(&Hb[(size_t)p1.x * 128 + fb]);
        uint4 v2 = *reinterpret_cast<const uint4*>(&Hb[(size_t)p2.x * 128 + fb]);
        uint4 v3 = *reinterpret_cast<const uint4*>(&Hb[(size_t)p3.x * 128 + fb]);
        acc8(acc, v0, __uint_as_float(p0.y));
        acc8(acc, v1, __uint_as_float(p1.y));
        acc8(acc, v2, __uint_as_float(p2.y));
        acc8(acc, v3, __uint_as_float(p3.y));
    }
    for (; j < e1; ++j) {
        uint2 p = csr[j];
        uint4 v = *reinterpret_cast<const uint4*>(&Hb[(size_t)p.x * 128 + fb]);
        acc8(acc, v, __uint_as_float(p.y));
    }
    uint4 o;
    o.x = (unsigned)f2bf(acc[0]) | ((unsigned)f2bf(acc[1]) << 16);
    o.y = (unsigned)f2bf(acc[2]) | ((unsigned)f2bf(acc[3]) << 16);
    o.z = (unsigned)f2bf(acc[4]) | ((unsigned)f2bf(acc[5]) << 16);
    o.w = (unsigned)f2bf(acc[6]) | ((unsigned)f2bf(acc[7]) << 16);
    *reinterpret_cast<uint4*>(&Ab[(size_t)node * 128 + fb]) = o;
}

// ---------------- BN stats (bf16 input) + finalize ----------------

__global__ __launch_bounds__(256) void stats_bf16(const unsigned short* __restrict__ A,
                                                  float* __restrict__ gsum,
                                                  float* __restrict__ gss, int N) {
    const int f8 = threadIdx.x & 15;
    const int rg = threadIdx.x >> 4;    // 0..15
    float s[8], ss[8];
#pragma unroll
    for (int i = 0; i < 8; i++) { s[i] = 0.f; ss[i] = 0.f; }
    for (int r = blockIdx.x * 16 + rg; r < N; r += gridDim.x * 16) {
        uint4 v = *reinterpret_cast<const uint4*>(&A[(size_t)r * 128 + f8 * 8]);
        unsigned q[4] = {v.x, v.y, v.z, v.w};
#pragma unroll
        for (int i = 0; i < 4; i++) {
            float a = bflo(q[i]), b = bfhi(q[i]);
            s[2 * i] += a; ss[2 * i] += a * a;
            s[2 * i + 1] += b; ss[2 * i + 1] += b * b;
        }
    }
    __shared__ float shs[256 * 8];
    __shared__ float shq[256 * 8];
#pragma unroll
    for (int i = 0; i < 8; i++) {
        shs[rg * 128 + f8 * 8 + i] = s[i];
        shq[rg * 128 + f8 * 8 + i] = ss[i];
    }
    __syncthreads();
    for (int off = 8; off >= 1; off >>= 1) {
        if (rg < off) {
#pragma unroll
            for (int i = 0; i < 8; i++) {
                shs[rg * 128 + f8 * 8 + i] += shs[(rg + off) * 128 + f8 * 8 + i];
                shq[rg * 128 + f8 * 8 + i] += shq[(rg + off) * 128 + f8 * 8 + i];
            }
        }
        __syncthreads();
    }
    if (rg == 0) {
#pragma unroll
        for (int i = 0; i < 8; i++) {
            atomicAdd(&gsum[f8 * 8 + i], shs[f8 * 8 + i]);
            atomicAdd(&gss[f8 * 8 + i], shq[f8 * 8 + i]);
        }
    }
}

__global__ void finalize_kernel(const float* __restrict__ gsum, const float* __restrict__ gss,
                                const float* __restrict__ g, const float* __restrict__ bt,
                                float* __restrict__ scale, float* __restrict__ shift, int N) {
    int f = threadIdx.x;
    float invn = 1.0f / (float)N;
    float m = gsum[f] * invn;
    float var = gss[f] * invn - m * m;
    float s = rsqrtf(var + EPSBN) * g[f];
    scale[f] = s;
    shift[f] = bt[f] - m * s;
}

// ---------------- pooling (BN+ReLU fused) + head ----------------

__device__ __forceinline__ int lower_bound_dev(const int* arr, int n, int key) {
    int lo = 0, hi = n;
    while (lo < hi) {
        int mid = (lo + hi) >> 1;
        if (arr[mid] < key) lo = mid + 1; else hi = mid;
    }
    return lo;
}

__global__ __launch_bounds__(128) void pool_bn_kernel(const unsigned short* __restrict__ A,
                                                      const float* __restrict__ scale,
                                                      const float* __restrict__ shift,
                                                      const int* __restrict__ batch,
                                                      float* __restrict__ pooled, int N) {
    int g = blockIdx.x >> 3, chunk = blockIdx.x & 7;
    int start = lower_bound_dev(batch, N, g);
    int end = lower_bound_dev(batch, N, g + 1);
    long long len = end - start;
    int c0 = start + (int)(len * chunk / 8);
    int c1 = start + (int)(len * (chunk + 1) / 8);
    int f = threadIdx.x;
    float sc = scale[f], sh = shift[f];
    float acc = 0.f;
    for (int r = c0; r < c1; ++r) {
        float v = __uint_as_float(((unsigned)A[(size_t)r * 128 + f]) << 16);
        acc += fmaxf(v * sc + sh, 0.f);
    }
    atomicAdd(&pooled[g * 128 + f], acc);
}

__global__ __launch_bounds__(128) void head1_kernel(const float* __restrict__ pooled,
                                                    const float* __restrict__ Wn,
                                                    const float* __restrict__ bnb,
                                                    float* __restrict__ p2) {
    int g = blockIdx.x, f = threadIdx.x;
    __shared__ float row[128];
    row[f] = pooled[g * 128 + f];
    __syncthreads();
    float acc = bnb[f];
    for (int k = 0; k < 128; k++) acc += row[k] * Wn[k * 128 + f];
    p2[g * 128 + f] = acc;
}

__global__ __launch_bounds__(64) void head2_kernel(const float* __restrict__ p2,
                                                   const float* __restrict__ Wf,
                                                   const float* __restrict__ bf,
                                                   float* __restrict__ out) {
    int g = blockIdx.x, t = threadIdx.x;
    __shared__ float row[128];
    row[t] = p2[g * 128 + t];
    row[t + 64] = p2[g * 128 + 64 + t];
    __syncthreads();
    float acc = -1e30f;
    if (t < NCLASSES) {
        acc = bf[t];
        for (int k = 0; k < 128; k++) acc += row[k] * Wf[k * NCLASSES + t];
    }
    float m = acc;
    for (int o = 32; o > 0; o >>= 1) m = fmaxf(m, __shfl_xor(m, o));
    float e = (t < NCLASSES) ? expf(acc - m) : 0.f;
    float ssum = e;
    for (int o = 32; o > 0; o >>= 1) ssum += __shfl_xor(ssum, o);
    if (t < NCLASSES) out[g * NCLASSES + t] = acc - m - logf(ssum);
}

// ---------------- launch ----------------

extern "C" void kernel_launch(void* const* d_in, const int* in_sizes, int n_in,
                              void* d_out, int out_size, void* d_ws, size_t ws_size,
                              hipStream_t stream) {
    const float* x    = (const float*)d_in[0];
    const int*   ei   = (const int*)d_in[1];
    const float* ew   = (const float*)d_in[2];
    const int*   batch= (const int*)d_in[3];
    const float* W1   = (const float*)d_in[4];
    const float* b1   = (const float*)d_in[5];
    const float* g1   = (const float*)d_in[6];
    const float* bt1  = (const float*)d_in[7];
    const float* W2   = (const float*)d_in[8];
    const float* b2   = (const float*)d_in[9];
    const float* g2   = (const float*)d_in[10];
    const float* bt2  = (const float*)d_in[11];
    const float* W3   = (const float*)d_in[12];
    const float* b3   = (const float*)d_in[13];
    const float* Wn   = (const float*)d_in[14];
    const float* bnb  = (const float*)d_in[15];
    const float* Wf   = (const float*)d_in[16];
    const float* bf   = (const float*)d_in[17];
    float* out = (float*)d_out;
    (void)in_sizes; (void)n_in; (void)out_size; (void)ws_size;

    char* ws = (char*)d_ws;
    size_t off = 0;
    auto alloc = [&](size_t bytes) -> char* {
        char* p = ws + off;
        off += (bytes + 255) / 256 * 256;
        return p;
    };
    const int N = NNODES, E = NEDGES;
    const size_t npad = (((size_t)N * 4) + 255) / 256 * 256;   // padded size of one N-int array

    unsigned short* Hb = (unsigned short*)alloc((size_t)N * 128 * 2);
    unsigned short* Ab = (unsigned short*)alloc((size_t)N * 128 * 2);
    // dinv, selfn, cnt, cursor: contiguous so one memset zeroes all
    char* zblock = alloc(npad * 4);
    float* dinv   = (float*)(zblock);
    float* selfn  = (float*)(zblock + npad);
    int*   cnt    = (int*)(zblock + 2 * npad);
    int*   cursor = (int*)(zblock + 3 * npad);
    int*   row_start = (int*)alloc((size_t)(N + 1) * 4);
    int*   bsum   = (int*)alloc(256 * 4);
    int*   bofs   = (int*)alloc(256 * 4);
    uint2* csr    = (uint2*)alloc((size_t)E * 8);
    float* gstats = (float*)alloc(256 * 4);
    float* gsum = gstats, *gss = gstats + 128;
    float* scaleB = (float*)alloc(128 * 4);
    float* shiftB = (float*)alloc(128 * 4);
    unsigned short* Wt = (unsigned short*)alloc(3 * 16384 * 2);
    unsigned short* Wt1 = Wt, *Wt2 = Wt + 16384, *Wt3 = Wt + 32768;
    float* pooled  = (float*)alloc(64 * 128 * 4);
    float* pooled2 = (float*)alloc(64 * 128 * 4);

    const int eblk = (E + 255) / 256;          // 3125
    const int gemmblk = (N + 127) / 128;       // 391
    const int aggblk = (N + 15) / 16;          // 3125

    // --- graph structure (shared by all 3 convs) ---
    (void)hipMemsetAsync(zblock, 0, npad * 4, stream);
    degcount_kernel<<<eblk, 256, 0, stream>>>(ei, ew, dinv, cnt, E);
    dinv_bsum_kernel<<<SCAN_NB, 256, 0, stream>>>(dinv, selfn, cnt, bsum, N);
    scan_bsum_kernel<<<1, 256, 0, stream>>>(bsum, bofs, row_start, SCAN_NB, N);
    scan_fin_kernel<<<SCAN_NB, 256, 0, stream>>>(cnt, bofs, row_start, N);
    fill_kernel<<<eblk, 256, 0, stream>>>(ei, ew, dinv, row_start, cursor, csr, E);
    wcast3_kernel<<<192, 256, 0, stream>>>(W1, W2, W3, Wt);

    // --- layer 1 ---
    gemm_mfma<true, false><<<gemmblk, 256, 0, stream>>>(x, Wt1, nullptr, nullptr, Hb, N);
    agg_kernel<<<aggblk, 256, 0, stream>>>(Hb, row_start, csr, selfn, b1, Ab, N);
    (void)hipMemsetAsync(gstats, 0, 256 * 4, stream);
    stats_bf16<<<256, 256, 0, stream>>>(Ab, gsum, gss, N);
    finalize_kernel<<<1, 128, 0, stream>>>(gsum, gss, g1, bt1, scaleB, shiftB, N);

    // --- layer 2 (BN1+ReLU fused into GEMM A-load) ---
    gemm_mfma<false, true><<<gemmblk, 256, 0, stream>>>(Ab, Wt2, scaleB, shiftB, Hb, N);
    agg_kernel<<<aggblk, 256, 0, stream>>>(Hb, row_start, csr, selfn, b2, Ab, N);
    (void)hipMemsetAsync(gstats, 0, 256 * 4, stream);
    stats_bf16<<<256, 256, 0, stream>>>(Ab, gsum, gss, N);
    finalize_kernel<<<1, 128, 0, stream>>>(gsum, gss, g2, bt2, scaleB, shiftB, N);

    // --- layer 3 (BN2+ReLU fused into GEMM A-load; layer-3 BN uses g2/bt2 per reference bug) ---
    gemm_mfma<false, true><<<gemmblk, 256, 0, stream>>>(Ab, Wt3, scaleB, shiftB, Hb, N);
    agg_kernel<<<aggblk, 256, 0, stream>>>(Hb, row_start, csr, selfn, b3, Ab, N);
    (void)hipMemsetAsync(gstats, 0, 256 * 4, stream);
    stats_bf16<<<256, 256, 0, stream>>>(Ab, gsum, gss, N);
    finalize_kernel<<<1, 128, 0, stream>>>(gsum, gss, g2, bt2, scaleB, shiftB, N);

    // --- pool (BN3+ReLU fused) + head ---
    (void)hipMemsetAsync(pooled, 0, 64 * 128 * 4, stream);
    pool_bn_kernel<<<NGRAPHS * 8, 128, 0, stream>>>(Ab, scaleB, shiftB, batch, pooled, N);
    head1_kernel<<<NGRAPHS, 128, 0, stream>>>(pooled, Wn, bnb, pooled2);
    head2_kernel<<<NGRAPHS, 64, 0, stream>>>(pooled2, Wf, bf, out);
}

// Round 5
// 427.219 us; speedup vs baseline: 2.3684x; 1.1491x over previous
//
#include <hip/hip_runtime.h>

#define NNODES 50000
#define NEDGES 800000
#define NGRAPHS 64
#define NCLASSES 38
#define EPSBN 1e-5f
#define SCAN_NB 196   // ceil(50000/256)
#define FIXSCALE 268435456.0f   // 2^28

typedef __attribute__((ext_vector_type(8))) short bf16x8;
typedef __attribute__((ext_vector_type(4))) float f32x4;

__device__ __forceinline__ float bflo(unsigned u) { return __uint_as_float(u << 16); }
__device__ __forceinline__ float bfhi(unsigned u) { return __uint_as_float(u & 0xffff0000u); }
__device__ __forceinline__ unsigned short f2bf(float f) {
    unsigned u = __float_as_uint(f);
    return (unsigned short)((u + 0x7fffu + ((u >> 16) & 1u)) >> 16);
}

// ---------------- graph preprocessing ----------------
// packed[d]: bits 40+ = in-edge count, bits 0..39 = sum(w) in 2^-28 fixed point.
// The returned old count is this edge's rank within its dst bucket.

__global__ void degcount_kernel(const int* __restrict__ ei, const float* __restrict__ ew,
                                unsigned long long* __restrict__ packed,
                                int* __restrict__ rank, int E) {
    int e = blockIdx.x * blockDim.x + threadIdx.x;
    if (e < E) {
        int d = ei[E + e];
        unsigned long long inc = (1ULL << 40) | (unsigned long long)(ew[e] * FIXSCALE);
        unsigned long long old = atomicAdd(&packed[d], inc);
        rank[e] = (int)(old >> 40);
    }
}

// dinv/selfn from packed wsum; per-block sum of counts (stage A of scan)
__global__ __launch_bounds__(256) void dinv_bsum_kernel(const unsigned long long* __restrict__ packed,
                                                        float* __restrict__ dinv,
                                                        float* __restrict__ selfn,
                                                        int* __restrict__ bsum, int N) {
    int i = blockIdx.x * 256 + threadIdx.x;
    int v = 0;
    if (i < N) {
        unsigned long long p = packed[i];
        v = (int)(p >> 40);
        float d = (float)(p & 0xFFFFFFFFFFULL) * (1.0f / FIXSCALE) + 1.0f;  // +1 self-loop
        float di = rsqrtf(fmaxf(d, 1e-12f));
        dinv[i] = di;
        selfn[i] = di * di;
    }
#pragma unroll
    for (int o = 1; o < 64; o <<= 1) v += __shfl_xor(v, o, 64);
    __shared__ int ws[4];
    int lane = threadIdx.x & 63, w = threadIdx.x >> 6;
    if (lane == 0) ws[w] = v;
    __syncthreads();
    if (threadIdx.x == 0) bsum[blockIdx.x] = ws[0] + ws[1] + ws[2] + ws[3];
}

// stage B: exclusive scan of the <=256 block sums; also writes row_start[N]=total
__global__ __launch_bounds__(256) void scan_bsum_kernel(const int* __restrict__ bsum,
                                                        int* __restrict__ bofs,
                                                        int* __restrict__ row_start, int NB, int N) {
    int t = threadIdx.x;
    int v = (t < NB) ? bsum[t] : 0;
    int lane = t & 63, w = t >> 6;
    int s = v;
#pragma unroll
    for (int o = 1; o < 64; o <<= 1) { int u = __shfl_up(s, o, 64); if (lane >= o) s += u; }
    __shared__ int wsum[4];
    if (lane == 63) wsum[w] = s;
    __syncthreads();
    int wofs = 0;
    for (int k = 0; k < w; k++) wofs += wsum[k];
    if (t < NB) bofs[t] = wofs + s - v;
    if (t == 255) row_start[N] = wofs + s;
}

// stage C: per-block exclusive scan + block offset -> row_start
__global__ __launch_bounds__(256) void scan_fin_kernel(const unsigned long long* __restrict__ packed,
                                                       const int* __restrict__ bofs,
                                                       int* __restrict__ row_start, int N) {
    int i = blockIdx.x * 256 + threadIdx.x;
    int v = (i < N) ? (int)(packed[i] >> 40) : 0;
    int lane = threadIdx.x & 63, w = threadIdx.x >> 6;
    int s = v;
#pragma unroll
    for (int o = 1; o < 64; o <<= 1) { int u = __shfl_up(s, o, 64); if (lane >= o) s += u; }
    __shared__ int wsum[4];
    if (lane == 63) wsum[w] = s;
    __syncthreads();
    int wofs = 0;
    for (int k = 0; k < w; k++) wofs += wsum[k];
    if (i < N) row_start[i] = bofs[blockIdx.x] + wofs + s - v;
}

// atomic-free fill: slot = row_start[dst] + rank[e]
__global__ void fill_kernel(const int* __restrict__ ei, const float* __restrict__ ew,
                            const float* __restrict__ dinv, const int* __restrict__ row_start,
                            const int* __restrict__ rank, uint2* __restrict__ csr, int E) {
    int e = blockIdx.x * blockDim.x + threadIdx.x;
    if (e >= E) return;
    int s = ei[e], d = ei[E + e];
    int slot = row_start[d] + rank[e];
    uint2 p;
    p.x = (unsigned)s;
    p.y = __float_as_uint(dinv[s] * ew[e] * dinv[d]);
    csr[slot] = p;
}

// all three W [k][c] fp32 -> Wt [c][k] bf16 in one launch
__global__ void wcast3_kernel(const float* __restrict__ W1, const float* __restrict__ W2,
                              const float* __restrict__ W3, unsigned short* __restrict__ Wt) {
    int idx = blockIdx.x * 256 + threadIdx.x;   // 0..49151
    int which = idx >> 14;
    int r = idx & 16383;
    const float* W = which == 0 ? W1 : (which == 1 ? W2 : W3);
    int c = r >> 7, k = r & 127;
    Wt[which * 16384 + c * 128 + k] = f2bf(W[k * 128 + c]);
}

// ---------------- MFMA GEMM: [M,128] @ [128,128] -> bf16 [M,128] ----------------
// optionally fuses y = relu(x*scale[k]+shift[k]) on the bf16 input (BN of previous layer)

template <bool IN_F32, bool FUSE_BN>
__global__ __launch_bounds__(256) void gemm_mfma(const void* __restrict__ Xin,
                                                 const unsigned short* __restrict__ Wt,
                                                 const float* __restrict__ scale,
                                                 const float* __restrict__ shift,
                                                 unsigned short* __restrict__ Hout, int M) {
    __shared__ unsigned short tile[128 * 128];
    const int lane = threadIdx.x & 63;
    const int wave = threadIdx.x >> 6;
    const int lr = lane & 15;
    const int lk = lane >> 4;     // 0..3
    const int row0 = blockIdx.x * 128 + wave * 32;

    f32x4 zero = {0.f, 0.f, 0.f, 0.f};
    f32x4 acc[2][8];
#pragma unroll
    for (int m = 0; m < 2; m++)
#pragma unroll
        for (int n = 0; n < 8; n++) acc[m][n] = zero;

#pragma unroll
    for (int ks = 0; ks < 4; ++ks) {
        const int kb = ks * 32 + lk * 8;
        bf16x8 a[2];
#pragma unroll
        for (int m = 0; m < 2; ++m) {
            union { bf16x8 v; unsigned short u[8]; uint4 q; } ua;
            int r = row0 + m * 16 + lr;
            if (r < M) {
                if (IN_F32) {
                    const float* X = (const float*)Xin;
                    float4 x0 = *reinterpret_cast<const float4*>(&X[(size_t)r * 128 + kb]);
                    float4 x1 = *reinterpret_cast<const float4*>(&X[(size_t)r * 128 + kb + 4]);
                    ua.u[0] = f2bf(x0.x); ua.u[1] = f2bf(x0.y); ua.u[2] = f2bf(x0.z); ua.u[3] = f2bf(x0.w);
                    ua.u[4] = f2bf(x1.x); ua.u[5] = f2bf(x1.y); ua.u[6] = f2bf(x1.z); ua.u[7] = f2bf(x1.w);
                } else {
                    const unsigned short* X = (const unsigned short*)Xin;
                    uint4 q = *reinterpret_cast<const uint4*>(&X[(size_t)r * 128 + kb]);
                    if (FUSE_BN) {
                        unsigned qq[4] = {q.x, q.y, q.z, q.w};
#pragma unroll
                        for (int i = 0; i < 4; i++) {
                            float y0 = fmaxf(bflo(qq[i]) * scale[kb + 2 * i] + shift[kb + 2 * i], 0.f);
                            float y1 = fmaxf(bfhi(qq[i]) * scale[kb + 2 * i + 1] + shift[kb + 2 * i + 1], 0.f);
                            ua.u[2 * i] = f2bf(y0);
                            ua.u[2 * i + 1] = f2bf(y1);
                        }
                    } else {
                        ua.q = q;
                    }
                }
            } else {
                ua.q = make_uint4(0, 0, 0, 0);
            }
            a[m] = ua.v;
        }
        bf16x8 b[8];
#pragma unroll
        for (int n = 0; n < 8; ++n) {
            union { bf16x8 v; uint4 q; } ub;
            ub.q = *reinterpret_cast<const uint4*>(&Wt[(size_t)(n * 16 + lr) * 128 + kb]);
            b[n] = ub.v;
        }
#pragma unroll
        for (int m = 0; m < 2; ++m)
#pragma unroll
            for (int n = 0; n < 8; ++n)
                acc[m][n] = __builtin_amdgcn_mfma_f32_16x16x32_bf16(a[m], b[n], acc[m][n], 0, 0, 0);
    }

    // epilogue: C/D layout col=lane&15, row=(lane>>4)*4+reg -> repack via LDS, 16B stores
#pragma unroll
    for (int m = 0; m < 2; ++m)
#pragma unroll
        for (int n = 0; n < 8; ++n)
#pragma unroll
            for (int r = 0; r < 4; ++r) {
                int rl = wave * 32 + m * 16 + lk * 4 + r;
                int c = n * 16 + lr;
                tile[rl * 128 + c] = f2bf(acc[m][n][r]);
            }
    __syncthreads();
#pragma unroll
    for (int it = 0; it < 8; ++it) {
        int idx = threadIdx.x + it * 256;     // 2048 16B-chunks
        int r = idx >> 4, c8 = (idx & 15) * 8;
        int gr = blockIdx.x * 128 + r;
        if (gr < M)
            *reinterpret_cast<uint4*>(&Hout[(size_t)gr * 128 + c8]) =
                *reinterpret_cast<const uint4*>(&tile[r * 128 + c8]);
    }
}

// ---------------- aggregation (bf16 rows, fp32 accum) ----------------

__device__ __forceinline__ void acc8(float* acc, uint4 v, float w) {
    unsigned q0 = v.x, q1 = v.y, q2 = v.z, q3 = v.w;
    acc[0] += w * bflo(q0); acc[1] += w * bfhi(q0);
    acc[2] += w * bflo(q1); acc[3] += w * bfhi(q1);
    acc[4] += w * bflo(q2); acc[5] += w * bfhi(q2);
    acc[6] += w * bflo(q3); acc[7] += w * bfhi(q3);
}

__global__ __launch_bounds__(256) void agg_kernel(const unsigned short* __restrict__ Hb,
                                                  const int* __restrict__ row_start,
                                                  const uint2* __restrict__ csr,
                                                  const float* __restrict__ selfn,
                                                  const float* __restrict__ bias,
                                                  unsigned short* __restrict__ Ab, int N) {
    int node = blockIdx.x * 16 + (threadIdx.x >> 4);
    int fb = (threadIdx.x & 15) * 8;
    if (node >= N) return;
    float acc[8];
    uint4 hv = *reinterpret_cast<const uint4*>(&Hb[(size_t)node * 128 + fb]);
    float sn = selfn[node];
    {
        unsigned q[4] = {hv.x, hv.y, hv.z, hv.w};
#pragma unroll
        for (int i = 0; i < 4; i++) {
            acc[2 * i] = sn * bflo(q[i]) + bias[fb + 2 * i];
            acc[2 * i + 1] = sn * bfhi(q[i]) + bias[fb + 2 * i + 1];
        }
    }
    int e0 = row_start[node], e1 = row_start[node + 1];
    int j = e0;
    for (; j + 4 <= e1; j += 4) {
        uint2 p0 = csr[j], p1 = csr[j + 1], p2 = csr[j + 2], p3 = csr[j + 3];
        uint4 v0 = *reinterpret_cast<const uint4*>(&Hb[(size_t)p0.x * 128 + fb]);
        uint4 v1 = *reinterpret_cast<const uint4*>(&Hb[(size_t)p1.x * 128 + fb]);
        uint4 v2 = *reinterpret_cast<const uint4*>(&Hb[(size_t)p2.x * 128 + fb]);
        uint4 v3 = *reinterpret_cast<const uint4*>(&Hb[(size_t)p3.x * 128 + fb]);
        acc8(acc, v0, __uint_as_float(p0.y));
        acc8(acc, v1, __uint_as_float(p1.y));
        acc8(acc, v2, __uint_as_float(p2.y));
        acc8(acc, v3, __uint_as_float(p3.y));
    }
    for (; j < e1; ++j) {
        uint2 p = csr[j];
        uint4 v = *reinterpret_cast<const uint4*>(&Hb[(size_t)p.x * 128 + fb]);
        acc8(acc, v, __uint_as_float(p.y));
    }
    uint4 o;
    o.x = (unsigned)f2bf(acc[0]) | ((unsigned)f2bf(acc[1]) << 16);
    o.y = (unsigned)f2bf(acc[2]) | ((unsigned)f2bf(acc[3]) << 16);
    o.z = (unsigned)f2bf(acc[4]) | ((unsigned)f2bf(acc[5]) << 16);
    o.w = (unsigned)f2bf(acc[6]) | ((unsigned)f2bf(acc[7]) << 16);
    *reinterpret_cast<uint4*>(&Ab[(size_t)node * 128 + fb]) = o;
}

// ---------------- BN stats (bf16 input) + finalize ----------------

__global__ __launch_bounds__(256) void stats_bf16(const unsigned short* __restrict__ A,
                                                  float* __restrict__ gsum,
                                                  float* __restrict__ gss, int N) {
    const int f8 = threadIdx.x & 15;
    const int rg = threadIdx.x >> 4;    // 0..15
    float s[8], ss[8];
#pragma unroll
    for (int i = 0; i < 8; i++) { s[i] = 0.f; ss[i] = 0.f; }
    for (int r = blockIdx.x * 16 + rg; r < N; r += gridDim.x * 16) {
        uint4 v = *reinterpret_cast<const uint4*>(&A[(size_t)r * 128 + f8 * 8]);
        unsigned q[4] = {v.x, v.y, v.z, v.w};
#pragma unroll
        for (int i = 0; i < 4; i++) {
            float a = bflo(q[i]), b = bfhi(q[i]);
            s[2 * i] += a; ss[2 * i] += a * a;
            s[2 * i + 1] += b; ss[2 * i + 1] += b * b;
        }
    }
    __shared__ float shs[256 * 8];
    __shared__ float shq[256 * 8];
#pragma unroll
    for (int i = 0; i < 8; i++) {
        shs[rg * 128 + f8 * 8 + i] = s[i];
        shq[rg * 128 + f8 * 8 + i] = ss[i];
    }
    __syncthreads();
    for (int off = 8; off >= 1; off >>= 1) {
        if (rg < off) {
#pragma unroll
            for (int i = 0; i < 8; i++) {
                shs[rg * 128 + f8 * 8 + i] += shs[(rg + off) * 128 + f8 * 8 + i];
                shq[rg * 128 + f8 * 8 + i] += shq[(rg + off) * 128 + f8 * 8 + i];
            }
        }
        __syncthreads();
    }
    if (rg == 0) {
#pragma unroll
        for (int i = 0; i < 8; i++) {
            atomicAdd(&gsum[f8 * 8 + i], shs[f8 * 8 + i]);
            atomicAdd(&gss[f8 * 8 + i], shq[f8 * 8 + i]);
        }
    }
}

__global__ void finalize_kernel(const float* __restrict__ gsum, const float* __restrict__ gss,
                                const float* __restrict__ g, const float* __restrict__ bt,
                                float* __restrict__ scale, float* __restrict__ shift, int N) {
    int f = threadIdx.x;
    float invn = 1.0f / (float)N;
    float m = gsum[f] * invn;
    float var = gss[f] * invn - m * m;
    float s = rsqrtf(var + EPSBN) * g[f];
    scale[f] = s;
    shift[f] = bt[f] - m * s;
}

// ---------------- pooling (BN+ReLU fused) + head ----------------

__device__ __forceinline__ int lower_bound_dev(const int* arr, int n, int key) {
    int lo = 0, hi = n;
    while (lo < hi) {
        int mid = (lo + hi) >> 1;
        if (arr[mid] < key) lo = mid + 1; else hi = mid;
    }
    return lo;
}

__global__ __launch_bounds__(128) void pool_bn_kernel(const unsigned short* __restrict__ A,
                                                      const float* __restrict__ scale,
                                                      const float* __restrict__ shift,
                                                      const int* __restrict__ batch,
                                                      float* __restrict__ pooled, int N) {
    int g = blockIdx.x >> 3, chunk = blockIdx.x & 7;
    int start = lower_bound_dev(batch, N, g);
    int end = lower_bound_dev(batch, N, g + 1);
    long long len = end - start;
    int c0 = start + (int)(len * chunk / 8);
    int c1 = start + (int)(len * (chunk + 1) / 8);
    int f = threadIdx.x;
    float sc = scale[f], sh = shift[f];
    float acc = 0.f;
    for (int r = c0; r < c1; ++r) {
        float v = __uint_as_float(((unsigned)A[(size_t)r * 128 + f]) << 16);
        acc += fmaxf(v * sc + sh, 0.f);
    }
    atomicAdd(&pooled[g * 128 + f], acc);
}

__global__ __launch_bounds__(128) void head1_kernel(const float* __restrict__ pooled,
                                                    const float* __restrict__ Wn,
                                                    const float* __restrict__ bnb,
                                                    float* __restrict__ p2) {
    int g = blockIdx.x, f = threadIdx.x;
    __shared__ float row[128];
    row[f] = pooled[g * 128 + f];
    __syncthreads();
    float acc = bnb[f];
    for (int k = 0; k < 128; k++) acc += row[k] * Wn[k * 128 + f];
    p2[g * 128 + f] = acc;
}

__global__ __launch_bounds__(64) void head2_kernel(const float* __restrict__ p2,
                                                   const float* __restrict__ Wf,
                                                   const float* __restrict__ bf,
                                                   float* __restrict__ out) {
    int g = blockIdx.x, t = threadIdx.x;
    __shared__ float row[128];
    row[t] = p2[g * 128 + t];
    row[t + 64] = p2[g * 128 + 64 + t];
    __syncthreads();
    float acc = -1e30f;
    if (t < NCLASSES) {
        acc = bf[t];
        for (int k = 0; k < 128; k++) acc += row[k] * Wf[k * NCLASSES + t];
    }
    float m = acc;
    for (int o = 32; o > 0; o >>= 1) m = fmaxf(m, __shfl_xor(m, o));
    float e = (t < NCLASSES) ? expf(acc - m) : 0.f;
    float ssum = e;
    for (int o = 32; o > 0; o >>= 1) ssum += __shfl_xor(ssum, o);
    if (t < NCLASSES) out[g * NCLASSES + t] = acc - m - logf(ssum);
}

// ---------------- launch ----------------

extern "C" void kernel_launch(void* const* d_in, const int* in_sizes, int n_in,
                              void* d_out, int out_size, void* d_ws, size_t ws_size,
                              hipStream_t stream) {
    const float* x    = (const float*)d_in[0];
    const int*   ei   = (const int*)d_in[1];
    const float* ew   = (const float*)d_in[2];
    const int*   batch= (const int*)d_in[3];
    const float* W1   = (const float*)d_in[4];
    const float* b1   = (const float*)d_in[5];
    const float* g1   = (const float*)d_in[6];
    const float* bt1  = (const float*)d_in[7];
    const float* W2   = (const float*)d_in[8];
    const float* b2   = (const float*)d_in[9];
    const float* g2   = (const float*)d_in[10];
    const float* bt2  = (const float*)d_in[11];
    const float* W3   = (const float*)d_in[12];
    const float* b3   = (const float*)d_in[13];
    const float* Wn   = (const float*)d_in[14];
    const float* bnb  = (const float*)d_in[15];
    const float* Wf   = (const float*)d_in[16];
    const float* bf   = (const float*)d_in[17];
    float* out = (float*)d_out;
    (void)in_sizes; (void)n_in; (void)out_size; (void)ws_size;

    char* ws = (char*)d_ws;
    size_t off = 0;
    auto alloc = [&](size_t bytes) -> char* {
        char* p = ws + off;
        off += (bytes + 255) / 256 * 256;
        return p;
    };
    const int N = NNODES, E = NEDGES;

    unsigned short* Hb = (unsigned short*)alloc((size_t)N * 128 * 2);
    unsigned short* Ab = (unsigned short*)alloc((size_t)N * 128 * 2);
    // zero block: packed[N] u64 | gstats3 | pooled  (one memset)
    size_t packed_b = ((size_t)N * 8 + 255) / 256 * 256;
    size_t gstats_b = (3 * 256 * 4 + 255) / 256 * 256;
    size_t pooled_b = (64 * 128 * 4 + 255) / 256 * 256;
    char* zblock = alloc(packed_b + gstats_b + pooled_b);
    unsigned long long* packed = (unsigned long long*)zblock;
    float* gstats3 = (float*)(zblock + packed_b);
    float* pooled  = (float*)(zblock + packed_b + gstats_b);
    size_t zbytes = packed_b + gstats_b + pooled_b;

    float* dinv   = (float*)alloc((size_t)N * 4);
    float* selfn  = (float*)alloc((size_t)N * 4);
    int*   rank   = (int*)alloc((size_t)E * 4);
    int*   row_start = (int*)alloc((size_t)(N + 1) * 4);
    int*   bsum   = (int*)alloc(256 * 4);
    int*   bofs   = (int*)alloc(256 * 4);
    uint2* csr    = (uint2*)alloc((size_t)E * 8);
    float* scaleB = (float*)alloc(128 * 4);
    float* shiftB = (float*)alloc(128 * 4);
    unsigned short* Wt = (unsigned short*)alloc(3 * 16384 * 2);
    unsigned short* Wt1 = Wt, *Wt2 = Wt + 16384, *Wt3 = Wt + 32768;
    float* pooled2 = (float*)alloc(64 * 128 * 4);

    const int eblk = (E + 255) / 256;          // 3125
    const int gemmblk = (N + 127) / 128;       // 391
    const int aggblk = (N + 15) / 16;          // 3125

    // --- graph structure (shared by all 3 convs) ---
    (void)hipMemsetAsync(zblock, 0, zbytes, stream);
    degcount_kernel<<<eblk, 256, 0, stream>>>(ei, ew, packed, rank, E);
    dinv_bsum_kernel<<<SCAN_NB, 256, 0, stream>>>(packed, dinv, selfn, bsum, N);
    scan_bsum_kernel<<<1, 256, 0, stream>>>(bsum, bofs, row_start, SCAN_NB, N);
    scan_fin_kernel<<<SCAN_NB, 256, 0, stream>>>(packed, bofs, row_start, N);
    fill_kernel<<<eblk, 256, 0, stream>>>(ei, ew, dinv, row_start, rank, csr, E);
    wcast3_kernel<<<192, 256, 0, stream>>>(W1, W2, W3, Wt);

    // --- layer 1 ---
    gemm_mfma<true, false><<<gemmblk, 256, 0, stream>>>(x, Wt1, nullptr, nullptr, Hb, N);
    agg_kernel<<<aggblk, 256, 0, stream>>>(Hb, row_start, csr, selfn, b1, Ab, N);
    stats_bf16<<<256, 256, 0, stream>>>(Ab, gstats3, gstats3 + 128, N);
    finalize_kernel<<<1, 128, 0, stream>>>(gstats3, gstats3 + 128, g1, bt1, scaleB, shiftB, N);

    // --- layer 2 (BN1+ReLU fused into GEMM A-load) ---
    gemm_mfma<false, true><<<gemmblk, 256, 0, stream>>>(Ab, Wt2, scaleB, shiftB, Hb, N);
    agg_kernel<<<aggblk, 256, 0, stream>>>(Hb, row_start, csr, selfn, b2, Ab, N);
    stats_bf16<<<256, 256, 0, stream>>>(Ab, gstats3 + 256, gstats3 + 384, N);
    finalize_kernel<<<1, 128, 0, stream>>>(gstats3 + 256, gstats3 + 384, g2, bt2, scaleB, shiftB, N);

    // --- layer 3 (BN2+ReLU fused into GEMM A-load; layer-3 BN uses g2/bt2 per reference bug) ---
    gemm_mfma<false, true><<<gemmblk, 256, 0, stream>>>(Ab, Wt3, scaleB, shiftB, Hb, N);
    agg_kernel<<<aggblk, 256, 0, stream>>>(Hb, row_start, csr, selfn, b3, Ab, N);
    stats_bf16<<<256, 256, 0, stream>>>(Ab, gstats3 + 512, gstats3 + 640, N);
    finalize_kernel<<<1, 128, 0, stream>>>(gstats3 + 512, gstats3 + 640, g2, bt2, scaleB, shiftB, N);

    // --- pool (BN3+ReLU fused) + head ---
    pool_bn_kernel<<<NGRAPHS * 8, 128, 0, stream>>>(Ab, scaleB, shiftB, batch, pooled, N);
    head1_kernel<<<NGRAPHS, 128, 0, stream>>>(pooled, Wn, bnb, pooled2);
    head2_kernel<<<NGRAPHS, 64, 0, stream>>>(pooled2, Wf, bf, out);
}

// Round 6
// 323.594 us; speedup vs baseline: 3.1268x; 1.3202x over previous
//
#include <hip/hip_runtime.h>

#define NNODES 50000
#define NEDGES 800000
#define NGRAPHS 64
#define NCLASSES 38
#define EPSBN 1e-5f
#define SCAN_NB 196   // ceil(50000/256)
#define AGG_NB 3125   // 50000/16
#define FIXSCALE 268435456.0f   // 2^28

typedef __attribute__((ext_vector_type(8))) short bf16x8;
typedef __attribute__((ext_vector_type(4))) float f32x4;

__device__ __forceinline__ float bflo(unsigned u) { return __uint_as_float(u << 16); }
__device__ __forceinline__ float bfhi(unsigned u) { return __uint_as_float(u & 0xffff0000u); }
__device__ __forceinline__ unsigned short f2bf(float f) {
    unsigned u = __float_as_uint(f);
    return (unsigned short)((u + 0x7fffu + ((u >> 16) & 1u)) >> 16);
}

// ---------------- graph preprocessing ----------------
// packed[d]: bits 40+ = in-edge count, bits 0..39 = sum(w) in 2^-28 fixed point.
// The returned old count is this edge's rank within its dst bucket.

__global__ void degcount_kernel(const int* __restrict__ ei, const float* __restrict__ ew,
                                unsigned long long* __restrict__ packed,
                                int* __restrict__ rank, int E) {
    int e = blockIdx.x * blockDim.x + threadIdx.x;
    if (e < E) {
        int d = ei[E + e];
        unsigned long long inc = (1ULL << 40) | (unsigned long long)(ew[e] * FIXSCALE);
        unsigned long long old = atomicAdd(&packed[d], inc);
        rank[e] = (int)(old >> 40);
    }
}

// dinv/selfn from packed wsum; per-block sum of counts (stage A of scan)
__global__ __launch_bounds__(256) void dinv_bsum_kernel(const unsigned long long* __restrict__ packed,
                                                        float* __restrict__ dinv,
                                                        float* __restrict__ selfn,
                                                        int* __restrict__ bsum, int N) {
    int i = blockIdx.x * 256 + threadIdx.x;
    int v = 0;
    if (i < N) {
        unsigned long long p = packed[i];
        v = (int)(p >> 40);
        float d = (float)(p & 0xFFFFFFFFFFULL) * (1.0f / FIXSCALE) + 1.0f;  // +1 self-loop
        float di = rsqrtf(fmaxf(d, 1e-12f));
        dinv[i] = di;
        selfn[i] = di * di;
    }
#pragma unroll
    for (int o = 1; o < 64; o <<= 1) v += __shfl_xor(v, o, 64);
    __shared__ int ws[4];
    int lane = threadIdx.x & 63, w = threadIdx.x >> 6;
    if (lane == 0) ws[w] = v;
    __syncthreads();
    if (threadIdx.x == 0) bsum[blockIdx.x] = ws[0] + ws[1] + ws[2] + ws[3];
}

// stage B: exclusive scan of the <=256 block sums; also writes row_start[N]=total
__global__ __launch_bounds__(256) void scan_bsum_kernel(const int* __restrict__ bsum,
                                                        int* __restrict__ bofs,
                                                        int* __restrict__ row_start, int NB, int N) {
    int t = threadIdx.x;
    int v = (t < NB) ? bsum[t] : 0;
    int lane = t & 63, w = t >> 6;
    int s = v;
#pragma unroll
    for (int o = 1; o < 64; o <<= 1) { int u = __shfl_up(s, o, 64); if (lane >= o) s += u; }
    __shared__ int wsum[4];
    if (lane == 63) wsum[w] = s;
    __syncthreads();
    int wofs = 0;
    for (int k = 0; k < w; k++) wofs += wsum[k];
    if (t < NB) bofs[t] = wofs + s - v;
    if (t == 255) row_start[N] = wofs + s;
}

// stage C: per-block exclusive scan + block offset -> row_start
__global__ __launch_bounds__(256) void scan_fin_kernel(const unsigned long long* __restrict__ packed,
                                                       const int* __restrict__ bofs,
                                                       int* __restrict__ row_start, int N) {
    int i = blockIdx.x * 256 + threadIdx.x;
    int v = (i < N) ? (int)(packed[i] >> 40) : 0;
    int lane = threadIdx.x & 63, w = threadIdx.x >> 6;
    int s = v;
#pragma unroll
    for (int o = 1; o < 64; o <<= 1) { int u = __shfl_up(s, o, 64); if (lane >= o) s += u; }
    __shared__ int wsum[4];
    if (lane == 63) wsum[w] = s;
    __syncthreads();
    int wofs = 0;
    for (int k = 0; k < w; k++) wofs += wsum[k];
    if (i < N) row_start[i] = bofs[blockIdx.x] + wofs + s - v;
}

// atomic-free fill: slot = row_start[dst] + rank[e]
__global__ void fill_kernel(const int* __restrict__ ei, const float* __restrict__ ew,
                            const float* __restrict__ dinv, const int* __restrict__ row_start,
                            const int* __restrict__ rank, uint2* __restrict__ csr, int E) {
    int e = blockIdx.x * blockDim.x + threadIdx.x;
    if (e >= E) return;
    int s = ei[e], d = ei[E + e];
    int slot = row_start[d] + rank[e];
    uint2 p;
    p.x = (unsigned)s;
    p.y = __float_as_uint(dinv[s] * ew[e] * dinv[d]);
    csr[slot] = p;
}

// all three W [k][c] fp32 -> Wt [c][k] bf16 in one launch
__global__ void wcast3_kernel(const float* __restrict__ W1, const float* __restrict__ W2,
                              const float* __restrict__ W3, unsigned short* __restrict__ Wt) {
    int idx = blockIdx.x * 256 + threadIdx.x;   // 0..49151
    int which = idx >> 14;
    int r = idx & 16383;
    const float* W = which == 0 ? W1 : (which == 1 ? W2 : W3);
    int c = r >> 7, k = r & 127;
    Wt[which * 16384 + c * 128 + k] = f2bf(W[k * 128 + c]);
}

// ---------------- MFMA GEMM: [M,128] @ [128,128] -> bf16 [M,128] ----------------
// optionally fuses y = relu(x*scale[k]+shift[k]) on the bf16 input (BN of previous layer)

template <bool IN_F32, bool FUSE_BN>
__global__ __launch_bounds__(256) void gemm_mfma(const void* __restrict__ Xin,
                                                 const unsigned short* __restrict__ Wt,
                                                 const float* __restrict__ scale,
                                                 const float* __restrict__ shift,
                                                 unsigned short* __restrict__ Hout, int M) {
    __shared__ unsigned short tile[128 * 128];
    const int lane = threadIdx.x & 63;
    const int wave = threadIdx.x >> 6;
    const int lr = lane & 15;
    const int lk = lane >> 4;     // 0..3
    const int row0 = blockIdx.x * 128 + wave * 32;

    f32x4 zero = {0.f, 0.f, 0.f, 0.f};
    f32x4 acc[2][8];
#pragma unroll
    for (int m = 0; m < 2; m++)
#pragma unroll
        for (int n = 0; n < 8; n++) acc[m][n] = zero;

#pragma unroll
    for (int ks = 0; ks < 4; ++ks) {
        const int kb = ks * 32 + lk * 8;
        bf16x8 a[2];
#pragma unroll
        for (int m = 0; m < 2; ++m) {
            union { bf16x8 v; unsigned short u[8]; uint4 q; } ua;
            int r = row0 + m * 16 + lr;
            if (r < M) {
                if (IN_F32) {
                    const float* X = (const float*)Xin;
                    float4 x0 = *reinterpret_cast<const float4*>(&X[(size_t)r * 128 + kb]);
                    float4 x1 = *reinterpret_cast<const float4*>(&X[(size_t)r * 128 + kb + 4]);
                    ua.u[0] = f2bf(x0.x); ua.u[1] = f2bf(x0.y); ua.u[2] = f2bf(x0.z); ua.u[3] = f2bf(x0.w);
                    ua.u[4] = f2bf(x1.x); ua.u[5] = f2bf(x1.y); ua.u[6] = f2bf(x1.z); ua.u[7] = f2bf(x1.w);
                } else {
                    const unsigned short* X = (const unsigned short*)Xin;
                    uint4 q = *reinterpret_cast<const uint4*>(&X[(size_t)r * 128 + kb]);
                    if (FUSE_BN) {
                        unsigned qq[4] = {q.x, q.y, q.z, q.w};
#pragma unroll
                        for (int i = 0; i < 4; i++) {
                            float y0 = fmaxf(bflo(qq[i]) * scale[kb + 2 * i] + shift[kb + 2 * i], 0.f);
                            float y1 = fmaxf(bfhi(qq[i]) * scale[kb + 2 * i + 1] + shift[kb + 2 * i + 1], 0.f);
                            ua.u[2 * i] = f2bf(y0);
                            ua.u[2 * i + 1] = f2bf(y1);
                        }
                    } else {
                        ua.q = q;
                    }
                }
            } else {
                ua.q = make_uint4(0, 0, 0, 0);
            }
            a[m] = ua.v;
        }
        bf16x8 b[8];
#pragma unroll
        for (int n = 0; n < 8; ++n) {
            union { bf16x8 v; uint4 q; } ub;
            ub.q = *reinterpret_cast<const uint4*>(&Wt[(size_t)(n * 16 + lr) * 128 + kb]);
            b[n] = ub.v;
        }
#pragma unroll
        for (int m = 0; m < 2; ++m)
#pragma unroll
            for (int n = 0; n < 8; ++n)
                acc[m][n] = __builtin_amdgcn_mfma_f32_16x16x32_bf16(a[m], b[n], acc[m][n], 0, 0, 0);
    }

    // epilogue: C/D layout col=lane&15, row=(lane>>4)*4+reg -> repack via LDS, 16B stores
#pragma unroll
    for (int m = 0; m < 2; ++m)
#pragma unroll
        for (int n = 0; n < 8; ++n)
#pragma unroll
            for (int r = 0; r < 4; ++r) {
                int rl = wave * 32 + m * 16 + lk * 4 + r;
                int c = n * 16 + lr;
                tile[rl * 128 + c] = f2bf(acc[m][n][r]);
            }
    __syncthreads();
#pragma unroll
    for (int it = 0; it < 8; ++it) {
        int idx = threadIdx.x + it * 256;     // 2048 16B-chunks
        int r = idx >> 4, c8 = (idx & 15) * 8;
        int gr = blockIdx.x * 128 + r;
        if (gr < M)
            *reinterpret_cast<uint4*>(&Hout[(size_t)gr * 128 + c8]) =
                *reinterpret_cast<const uint4*>(&tile[r * 128 + c8]);
    }
}

// ---------------- aggregation (bf16 rows, fp32 accum) + fused BN partial stats ----------------

__device__ __forceinline__ void acc8(float* acc, uint4 v, float w) {
    unsigned q0 = v.x, q1 = v.y, q2 = v.z, q3 = v.w;
    acc[0] += w * bflo(q0); acc[1] += w * bfhi(q0);
    acc[2] += w * bflo(q1); acc[3] += w * bfhi(q1);
    acc[4] += w * bflo(q2); acc[5] += w * bfhi(q2);
    acc[6] += w * bflo(q3); acc[7] += w * bfhi(q3);
}

// 16 nodes per block (256 threads = 16 nodes x 16 f-groups of 8).
// Emits per-block partial sum/sumsq of the conv output (BN input) -> psum/pss[block][128].
__global__ __launch_bounds__(256) void agg_kernel(const unsigned short* __restrict__ Hb,
                                                  const int* __restrict__ row_start,
                                                  const uint2* __restrict__ csr,
                                                  const float* __restrict__ selfn,
                                                  const float* __restrict__ bias,
                                                  unsigned short* __restrict__ Ab,
                                                  float* __restrict__ psum,
                                                  float* __restrict__ pss, int N) {
    int node = blockIdx.x * 16 + (threadIdx.x >> 4);
    int fb = (threadIdx.x & 15) * 8;
    const int lane = threadIdx.x & 63;
    const int wave = threadIdx.x >> 6;

    float acc[8];
    uint4 hv = *reinterpret_cast<const uint4*>(&Hb[(size_t)node * 128 + fb]);
    float sn = selfn[node];
    {
        unsigned q[4] = {hv.x, hv.y, hv.z, hv.w};
#pragma unroll
        for (int i = 0; i < 4; i++) {
            acc[2 * i] = sn * bflo(q[i]) + bias[fb + 2 * i];
            acc[2 * i + 1] = sn * bfhi(q[i]) + bias[fb + 2 * i + 1];
        }
    }
    int e0 = row_start[node], e1 = row_start[node + 1];
    int j = e0;
    for (; j + 4 <= e1; j += 4) {
        uint2 p0 = csr[j], p1 = csr[j + 1], p2 = csr[j + 2], p3 = csr[j + 3];
        uint4 v0 = *reinterpret_cast<const uint4*>(&Hb[(size_t)p0.x * 128 + fb]);
        uint4 v1 = *reinterpret_cast<const uint4*>(&Hb[(size_t)p1.x * 128 + fb]);
        uint4 v2 = *reinterpret_cast<const uint4*>(&Hb[(size_t)p2.x * 128 + fb]);
        uint4 v3 = *reinterpret_cast<const uint4*>(&Hb[(size_t)p3.x * 128 + fb]);
        acc8(acc, v0, __uint_as_float(p0.y));
        acc8(acc, v1, __uint_as_float(p1.y));
        acc8(acc, v2, __uint_as_float(p2.y));
        acc8(acc, v3, __uint_as_float(p3.y));
    }
    for (; j < e1; ++j) {
        uint2 p = csr[j];
        uint4 v = *reinterpret_cast<const uint4*>(&Hb[(size_t)p.x * 128 + fb]);
        acc8(acc, v, __uint_as_float(p.y));
    }
    uint4 o;
    o.x = (unsigned)f2bf(acc[0]) | ((unsigned)f2bf(acc[1]) << 16);
    o.y = (unsigned)f2bf(acc[2]) | ((unsigned)f2bf(acc[3]) << 16);
    o.z = (unsigned)f2bf(acc[4]) | ((unsigned)f2bf(acc[5]) << 16);
    o.w = (unsigned)f2bf(acc[6]) | ((unsigned)f2bf(acc[7]) << 16);
    *reinterpret_cast<uint4*>(&Ab[(size_t)node * 128 + fb]) = o;

    // ---- fused BN partial stats (fp32, pre-round) ----
    float s[8], q2[8];
#pragma unroll
    for (int i = 0; i < 8; i++) { s[i] = acc[i]; q2[i] = acc[i] * acc[i]; }
    // reduce the wave's 4 nodes (lanes differ by 16, 32)
#pragma unroll
    for (int i = 0; i < 8; i++) {
        s[i] += __shfl_xor(s[i], 16, 64);  q2[i] += __shfl_xor(q2[i], 16, 64);
        s[i] += __shfl_xor(s[i], 32, 64);  q2[i] += __shfl_xor(q2[i], 32, 64);
    }
    __shared__ float shs[512], shq[512];
    if (lane < 16) {
#pragma unroll
        for (int i = 0; i < 8; i++) {
            shs[wave * 128 + lane * 8 + i] = s[i];
            shq[wave * 128 + lane * 8 + i] = q2[i];
        }
    }
    __syncthreads();
    int t = threadIdx.x;
    if (t < 128) {
        float ts = shs[t] + shs[128 + t] + shs[256 + t] + shs[384 + t];
        float tq = shq[t] + shq[128 + t] + shq[256 + t] + shq[384 + t];
        psum[(size_t)blockIdx.x * 128 + t] = ts;
        pss[(size_t)blockIdx.x * 128 + t] = tq;
    }
}

// reduce 3125 block-partials -> partial2[2][64][128]
__global__ __launch_bounds__(256) void reduce_kernel(const float* __restrict__ psum,
                                                     const float* __restrict__ pss,
                                                     float* __restrict__ p2) {
    int t = threadIdx.x;
    int which = t >> 7, f = t & 127;
    const float* P = which ? pss : psum;
    float a = 0.f;
    for (int r = blockIdx.x; r < AGG_NB; r += 64) a += P[(size_t)r * 128 + f];
    p2[(size_t)which * 8192 + blockIdx.x * 128 + f] = a;
}

__global__ void finalize_kernel(const float* __restrict__ p2,
                                const float* __restrict__ g, const float* __restrict__ bt,
                                float* __restrict__ scale, float* __restrict__ shift, int N) {
    int f = threadIdx.x;
    float s = 0.f, ss = 0.f;
    for (int b = 0; b < 64; b++) {
        s += p2[b * 128 + f];
        ss += p2[8192 + b * 128 + f];
    }
    float invn = 1.0f / (float)N;
    float m = s * invn;
    float var = ss * invn - m * m;
    float sc = rsqrtf(var + EPSBN) * g[f];
    scale[f] = sc;
    shift[f] = bt[f] - m * sc;
}

// ---------------- pooling (BN+ReLU fused) + head ----------------

__device__ __forceinline__ int lower_bound_dev(const int* arr, int n, int key) {
    int lo = 0, hi = n;
    while (lo < hi) {
        int mid = (lo + hi) >> 1;
        if (arr[mid] < key) lo = mid + 1; else hi = mid;
    }
    return lo;
}

__global__ __launch_bounds__(128) void pool_bn_kernel(const unsigned short* __restrict__ A,
                                                      const float* __restrict__ scale,
                                                      const float* __restrict__ shift,
                                                      const int* __restrict__ batch,
                                                      float* __restrict__ pooled, int N) {
    int g = blockIdx.x >> 3, chunk = blockIdx.x & 7;
    int start = lower_bound_dev(batch, N, g);
    int end = lower_bound_dev(batch, N, g + 1);
    long long len = end - start;
    int c0 = start + (int)(len * chunk / 8);
    int c1 = start + (int)(len * (chunk + 1) / 8);
    int f = threadIdx.x;
    float sc = scale[f], sh = shift[f];
    float acc = 0.f;
    for (int r = c0; r < c1; ++r) {
        float v = __uint_as_float(((unsigned)A[(size_t)r * 128 + f]) << 16);
        acc += fmaxf(v * sc + sh, 0.f);
    }
    atomicAdd(&pooled[g * 128 + f], acc);
}

__global__ __launch_bounds__(128) void head1_kernel(const float* __restrict__ pooled,
                                                    const float* __restrict__ Wn,
                                                    const float* __restrict__ bnb,
                                                    float* __restrict__ p2) {
    int g = blockIdx.x, f = threadIdx.x;
    __shared__ float row[128];
    row[f] = pooled[g * 128 + f];
    __syncthreads();
    float acc = bnb[f];
    for (int k = 0; k < 128; k++) acc += row[k] * Wn[k * 128 + f];
    p2[g * 128 + f] = acc;
}

__global__ __launch_bounds__(64) void head2_kernel(const float* __restrict__ p2,
                                                   const float* __restrict__ Wf,
                                                   const float* __restrict__ bf,
                                                   float* __restrict__ out) {
    int g = blockIdx.x, t = threadIdx.x;
    __shared__ float row[128];
    row[t] = p2[g * 128 + t];
    row[t + 64] = p2[g * 128 + 64 + t];
    __syncthreads();
    float acc = -1e30f;
    if (t < NCLASSES) {
        acc = bf[t];
        for (int k = 0; k < 128; k++) acc += row[k] * Wf[k * NCLASSES + t];
    }
    float m = acc;
    for (int o = 32; o > 0; o >>= 1) m = fmaxf(m, __shfl_xor(m, o));
    float e = (t < NCLASSES) ? expf(acc - m) : 0.f;
    float ssum = e;
    for (int o = 32; o > 0; o >>= 1) ssum += __shfl_xor(ssum, o);
    if (t < NCLASSES) out[g * NCLASSES + t] = acc - m - logf(ssum);
}

// ---------------- launch ----------------

extern "C" void kernel_launch(void* const* d_in, const int* in_sizes, int n_in,
                              void* d_out, int out_size, void* d_ws, size_t ws_size,
                              hipStream_t stream) {
    const float* x    = (const float*)d_in[0];
    const int*   ei   = (const int*)d_in[1];
    const float* ew   = (const float*)d_in[2];
    const int*   batch= (const int*)d_in[3];
    const float* W1   = (const float*)d_in[4];
    const float* b1   = (const float*)d_in[5];
    const float* g1   = (const float*)d_in[6];
    const float* bt1  = (const float*)d_in[7];
    const float* W2   = (const float*)d_in[8];
    const float* b2   = (const float*)d_in[9];
    const float* g2   = (const float*)d_in[10];
    const float* bt2  = (const float*)d_in[11];
    const float* W3   = (const float*)d_in[12];
    const float* b3   = (const float*)d_in[13];
    const float* Wn   = (const float*)d_in[14];
    const float* bnb  = (const float*)d_in[15];
    const float* Wf   = (const float*)d_in[16];
    const float* bf   = (const float*)d_in[17];
    float* out = (float*)d_out;
    (void)in_sizes; (void)n_in; (void)out_size; (void)ws_size;

    char* ws = (char*)d_ws;
    size_t off = 0;
    auto alloc = [&](size_t bytes) -> char* {
        char* p = ws + off;
        off += (bytes + 255) / 256 * 256;
        return p;
    };
    const int N = NNODES, E = NEDGES;

    unsigned short* Hb = (unsigned short*)alloc((size_t)N * 128 * 2);
    unsigned short* Ab = (unsigned short*)alloc((size_t)N * 128 * 2);
    // zero block: packed[N] u64 | pooled  (one memset)
    size_t packed_b = ((size_t)N * 8 + 255) / 256 * 256;
    size_t pooled_b = (64 * 128 * 4 + 255) / 256 * 256;
    char* zblock = alloc(packed_b + pooled_b);
    unsigned long long* packed = (unsigned long long*)zblock;
    float* pooled  = (float*)(zblock + packed_b);
    size_t zbytes = packed_b + pooled_b;

    float* dinv   = (float*)alloc((size_t)N * 4);
    float* selfn  = (float*)alloc((size_t)N * 4);
    int*   rank   = (int*)alloc((size_t)E * 4);
    int*   row_start = (int*)alloc((size_t)(N + 1) * 4);
    int*   bsum   = (int*)alloc(256 * 4);
    int*   bofs   = (int*)alloc(256 * 4);
    uint2* csr    = (uint2*)alloc((size_t)E * 8);
    float* psum   = (float*)alloc((size_t)AGG_NB * 128 * 4);
    float* pss    = (float*)alloc((size_t)AGG_NB * 128 * 4);
    float* part2  = (float*)alloc(2 * 64 * 128 * 4);
    float* scaleB = (float*)alloc(128 * 4);
    float* shiftB = (float*)alloc(128 * 4);
    unsigned short* Wt = (unsigned short*)alloc(3 * 16384 * 2);
    unsigned short* Wt1 = Wt, *Wt2 = Wt + 16384, *Wt3 = Wt + 32768;
    float* pooled2 = (float*)alloc(64 * 128 * 4);

    const int eblk = (E + 255) / 256;          // 3125
    const int gemmblk = (N + 127) / 128;       // 391

    // --- graph structure (shared by all 3 convs) ---
    (void)hipMemsetAsync(zblock, 0, zbytes, stream);
    degcount_kernel<<<eblk, 256, 0, stream>>>(ei, ew, packed, rank, E);
    dinv_bsum_kernel<<<SCAN_NB, 256, 0, stream>>>(packed, dinv, selfn, bsum, N);
    scan_bsum_kernel<<<1, 256, 0, stream>>>(bsum, bofs, row_start, SCAN_NB, N);
    scan_fin_kernel<<<SCAN_NB, 256, 0, stream>>>(packed, bofs, row_start, N);
    fill_kernel<<<eblk, 256, 0, stream>>>(ei, ew, dinv, row_start, rank, csr, E);
    wcast3_kernel<<<192, 256, 0, stream>>>(W1, W2, W3, Wt);

    // --- layer 1 ---
    gemm_mfma<true, false><<<gemmblk, 256, 0, stream>>>(x, Wt1, nullptr, nullptr, Hb, N);
    agg_kernel<<<AGG_NB, 256, 0, stream>>>(Hb, row_start, csr, selfn, b1, Ab, psum, pss, N);
    reduce_kernel<<<64, 256, 0, stream>>>(psum, pss, part2);
    finalize_kernel<<<1, 128, 0, stream>>>(part2, g1, bt1, scaleB, shiftB, N);

    // --- layer 2 (BN1+ReLU fused into GEMM A-load) ---
    gemm_mfma<false, true><<<gemmblk, 256, 0, stream>>>(Ab, Wt2, scaleB, shiftB, Hb, N);
    agg_kernel<<<AGG_NB, 256, 0, stream>>>(Hb, row_start, csr, selfn, b2, Ab, psum, pss, N);
    reduce_kernel<<<64, 256, 0, stream>>>(psum, pss, part2);
    finalize_kernel<<<1, 128, 0, stream>>>(part2, g2, bt2, scaleB, shiftB, N);

    // --- layer 3 (BN2+ReLU fused into GEMM A-load; layer-3 BN uses g2/bt2 per reference bug) ---
    gemm_mfma<false, true><<<gemmblk, 256, 0, stream>>>(Ab, Wt3, scaleB, shiftB, Hb, N);
    agg_kernel<<<AGG_NB, 256, 0, stream>>>(Hb, row_start, csr, selfn, b3, Ab, psum, pss, N);
    reduce_kernel<<<64, 256, 0, stream>>>(psum, pss, part2);
    finalize_kernel<<<1, 128, 0, stream>>>(part2, g2, bt2, scaleB, shiftB, N);

    // --- pool (BN3+ReLU fused) + head ---
    pool_bn_kernel<<<NGRAPHS * 8, 128, 0, stream>>>(Ab, scaleB, shiftB, batch, pooled, N);
    head1_kernel<<<NGRAPHS, 128, 0, stream>>>(pooled, Wn, bnb, pooled2);
    head2_kernel<<<NGRAPHS, 64, 0, stream>>>(pooled2, Wf, bf, out);
}